// Round 1
// baseline (837.565 us; speedup 1.0000x reference)
//
#include <hip/hip_runtime.h>
#include <hip/hip_bf16.h>

#define DIM 96

// ---------------- degree + count per dst ----------------
__global__ void k_deg(const int* __restrict__ ei, const float* __restrict__ ew,
                      float* __restrict__ deg, int* __restrict__ cnt, int E) {
    int e = blockIdx.x * 256 + threadIdx.x;
    if (e >= E) return;
    int d = ei[E + e];
    atomicAdd(&deg[d], ew[e]);
    atomicAdd(&cnt[d], 1);
}

// ---------------- deg -> dinv, dinv2 (in place over deg) ----------------
__global__ void k_dinv(float* __restrict__ dinv, float* __restrict__ dinv2, int n) {
    int i = blockIdx.x * 256 + threadIdx.x;
    if (i >= n) return;
    float d = dinv[i] + 1.0f;            // +1 self loop
    float r = rsqrtf(d);
    dinv[i] = r;
    dinv2[i] = r * r;
}

// ---------------- exclusive scan (two arrays, one block each) ----------------
__global__ __launch_bounds__(1024) void k_scan(
    const int* __restrict__ cnt0, int* __restrict__ rp0, int* __restrict__ cur0,
    const int* __restrict__ cnt1, int* __restrict__ rp1, int* __restrict__ cur1, int n)
{
    const int* cnt = blockIdx.x ? cnt1 : cnt0;
    int* rp  = blockIdx.x ? rp1  : rp0;
    int* cur = blockIdx.x ? cur1 : cur0;
    __shared__ int wsum[16];
    __shared__ int carry_s;
    int tid = threadIdx.x, lane = tid & 63, wid = tid >> 6;
    if (tid == 0) { carry_s = 0; rp[0] = 0; }
    __syncthreads();
    for (int base = 0; base < n; base += 1024) {
        int i = base + tid;
        int v = (i < n) ? cnt[i] : 0;
        int xv = v;
        #pragma unroll
        for (int d = 1; d < 64; d <<= 1) {
            int t = __shfl_up(xv, d);
            if (lane >= d) xv += t;
        }
        if (lane == 63) wsum[wid] = xv;
        __syncthreads();
        if (wid == 0) {
            int y = (lane < 16) ? wsum[lane] : 0;
            #pragma unroll
            for (int d = 1; d < 16; d <<= 1) {
                int t = __shfl_up(y, d);
                if (lane >= d) y += t;
            }
            if (lane < 16) wsum[lane] = y;
        }
        __syncthreads();
        int woff = (wid > 0) ? wsum[wid - 1] : 0;
        int incl = xv + woff + carry_s;
        if (i < n) { rp[i + 1] = incl; cur[i] = incl - v; }
        __syncthreads();
        if (tid == 1023) carry_s = incl;
        __syncthreads();
    }
}

// ---------------- scatter edges into CSR (by dst) ----------------
__global__ void k_scatter(const int* __restrict__ ei, const float* __restrict__ ew,
                          const float* __restrict__ dinv, int* __restrict__ cur,
                          int* __restrict__ col, float* __restrict__ val, int E) {
    int e = blockIdx.x * 256 + threadIdx.x;
    if (e >= E) return;
    int s = ei[e];
    int d = ei[E + e];
    float w = ew[e];
    int slot = atomicAdd(&cur[d], 1);
    col[slot] = s;
    val[slot] = dinv[s] * w * dinv[d];
}

// ---------------- fold W_o@Wf_top, W_n@Wf_bot, combined bias ----------------
__global__ void k_combine(const float* __restrict__ Wo, const float* __restrict__ Wn,
                          const float* __restrict__ Wf, const float* __restrict__ bo,
                          const float* __restrict__ bn, const float* __restrict__ bf,
                          float* __restrict__ Wco, float* __restrict__ Wcn,
                          float* __restrict__ bc) {
    int g = blockIdx.x * 256 + threadIdx.x;
    if (g >= DIM * DIM) return;
    int i = g / DIM, j = g % DIM;
    float so = 0.f, sn = 0.f;
    for (int k = 0; k < DIM; ++k) {
        so += Wo[i * DIM + k] * Wf[k * DIM + j];
        sn += Wn[i * DIM + k] * Wf[(DIM + k) * DIM + j];
    }
    Wco[g] = so;
    Wcn[g] = sn;
    if (i == 0) {
        float s = bf[j];
        for (int k = 0; k < DIM; ++k) {
            s += bo[k] * Wf[k * DIM + j] + bn[k] * Wf[(DIM + k) * DIM + j];
        }
        bc[j] = s;
    }
}

// ---------------- graph boundary detection (batch is sorted) ----------------
__global__ void k_bounds(const int* __restrict__ batch, int* __restrict__ gs,
                         int* __restrict__ ge, int n) {
    int i = blockIdx.x * 256 + threadIdx.x;
    if (i >= n) return;
    int b = batch[i];
    if (i == 0 || batch[i - 1] != b) atomicMin(&gs[b], i);
    if (i == n - 1 || batch[i + 1] != b) atomicMax(&ge[b], i + 1);
}

// ---------------- aggregation: out[v] = sum_e norm*X[src] + dinv2[v]*X[v] ----------------
__global__ __launch_bounds__(256) void k_agg(
    const float* __restrict__ X, const int* __restrict__ rp,
    const int* __restrict__ col, const float* __restrict__ val,
    const float* __restrict__ dinv2, float* __restrict__ out, int n)
{
    int wid = (blockIdx.x * 256 + threadIdx.x) >> 6;   // one wave per node
    int lane = threadIdx.x & 63;
    if (wid >= n) return;
    int c0 = lane, c1 = 64 + lane;
    bool has2 = (c1 < DIM);
    const float* xr = X + (size_t)wid * DIM;
    float d2 = dinv2[wid];
    float a0 = d2 * xr[c0];
    float a1 = has2 ? d2 * xr[c1] : 0.f;
    int s = rp[wid], e = rp[wid + 1];
    for (int j = s; j < e; ++j) {
        int u = col[j];
        float w = val[j];
        const float* xs = X + (size_t)u * DIM;
        a0 += w * xs[c0];
        if (has2) a1 += w * xs[c1];
    }
    out[(size_t)wid * DIM + c0] = a0;
    if (has2) out[(size_t)wid * DIM + c1] = a1;
}

// ---------------- out = relu(A@Wo + B@Wn + bias) ----------------
#define RB 24
__global__ __launch_bounds__(192) void k_matmul(
    const float* __restrict__ A, const float* __restrict__ B,
    const float* __restrict__ Wo, const float* __restrict__ Wn,
    const float* __restrict__ bias, float* __restrict__ out, int n)
{
    __shared__ float lA[RB * 100];
    __shared__ float lB[RB * 100];
    __shared__ float lW[2][32 * DIM];
    int tid = threadIdx.x;
    int r0 = blockIdx.x * RB;
    int rows = min(RB, n - r0);
    int limit = rows * DIM;
    #pragma unroll
    for (int j = 0; j < 3; ++j) {
        int o = (tid + j * 192) * 4;
        float4 va = make_float4(0.f, 0.f, 0.f, 0.f), vb = va;
        if (o < limit) {
            va = *(const float4*)(A + (size_t)r0 * DIM + o);
            vb = *(const float4*)(B + (size_t)r0 * DIM + o);
        }
        int r = o / DIM, c = o % DIM;
        *(float4*)&lA[r * 100 + c] = va;
        *(float4*)&lB[r * 100 + c] = vb;
    }
    int cg = tid % 24, rg = tid / 24;       // 24 col-groups x 8 row-groups
    float acc[3][4] = {};
    for (int kc = 0; kc < DIM; kc += 32) {
        __syncthreads();
        #pragma unroll
        for (int j = 0; j < 4; ++j) {
            int o = (tid + j * 192) * 4;
            *(float4*)&lW[0][o] = *(const float4*)(Wo + kc * DIM + o);
            *(float4*)&lW[1][o] = *(const float4*)(Wn + kc * DIM + o);
        }
        __syncthreads();
        for (int k = 0; k < 32; ++k) {
            float4 wo = *(const float4*)&lW[0][k * DIM + cg * 4];
            float4 wn = *(const float4*)&lW[1][k * DIM + cg * 4];
            int kk = kc + k;
            #pragma unroll
            for (int r = 0; r < 3; ++r) {
                float a = lA[(rg * 3 + r) * 100 + kk];
                float b = lB[(rg * 3 + r) * 100 + kk];
                acc[r][0] += a * wo.x + b * wn.x;
                acc[r][1] += a * wo.y + b * wn.y;
                acc[r][2] += a * wo.z + b * wn.z;
                acc[r][3] += a * wo.w + b * wn.w;
            }
        }
    }
    int cb = cg * 4;
    float4 bs = *(const float4*)(bias + cb);
    #pragma unroll
    for (int r = 0; r < 3; ++r) {
        int row = rg * 3 + r;
        if (row < rows) {
            float4 v;
            v.x = fmaxf(acc[r][0] + bs.x, 0.f);
            v.y = fmaxf(acc[r][1] + bs.y, 0.f);
            v.z = fmaxf(acc[r][2] + bs.z, 0.f);
            v.w = fmaxf(acc[r][3] + bs.w, 0.f);
            *(float4*)(out + (size_t)(r0 + row) * DIM + cb) = v;
        }
    }
}

// ---------------- mean pool: partial sums + atomic ----------------
__global__ void k_pool(const float* __restrict__ X, const int* __restrict__ gs,
                       const int* __restrict__ ge, float* __restrict__ outp) {
    int g = blockIdx.y;
    int c = threadIdx.x;       // 96 threads
    float acc = 0.f;
    int s = gs[g], e = ge[g];
    for (int i = s + blockIdx.x; i < e; i += gridDim.x) {
        acc += X[(size_t)i * DIM + c];
    }
    atomicAdd(&outp[g * DIM + c], acc);
}

__global__ void k_divide(float* __restrict__ out, const int* __restrict__ gs,
                         const int* __restrict__ ge, int total) {
    int idx = blockIdx.x * 256 + threadIdx.x;
    if (idx >= total) return;
    int g = (idx / DIM) % 64;
    int c = ge[g] - gs[g];
    if (c < 1) c = 1;
    out[idx] /= (float)c;
}

extern "C" void kernel_launch(void* const* d_in, const int* in_sizes, int n_in,
                              void* d_out, int out_size, void* d_ws, size_t ws_size,
                              hipStream_t stream)
{
    const float* x     = (const float*)d_in[0];
    const int*   ei    = (const int*)d_in[1];
    const float* ew    = (const float*)d_in[2];
    const int*   batch = (const int*)d_in[3];
    const int*   ein   = (const int*)d_in[4];
    const float* ewn   = (const float*)d_in[5];
    const float* W0o = (const float*)d_in[7];
    const float* b0o = (const float*)d_in[8];
    const float* W0n = (const float*)d_in[9];
    const float* b0n = (const float*)d_in[10];
    const float* W0f = (const float*)d_in[11];
    const float* b0f = (const float*)d_in[12];
    const float* W1o = (const float*)d_in[13];
    const float* b1o = (const float*)d_in[14];
    const float* W1n = (const float*)d_in[15];
    const float* b1n = (const float*)d_in[16];
    const float* W1f = (const float*)d_in[17];
    const float* b1f = (const float*)d_in[18];

    const int N = in_sizes[0] / DIM;
    const int E = in_sizes[2];
    float* out = (float*)d_out;

    char* ws = (char*)d_ws;
    size_t off = 0;
    auto alloc = [&](size_t bytes) -> char* {
        char* p = ws + off;
        off += (bytes + 255) & ~(size_t)255;
        return p;
    };
    float* fA      = (float*)alloc((size_t)N * DIM * 4);
    float* fB      = (float*)alloc((size_t)N * DIM * 4);
    float* fH      = (float*)alloc((size_t)N * DIM * 4);
    float* dinv_o  = (float*)alloc((size_t)N * 4);     // also deg storage
    float* dinv2_o = (float*)alloc((size_t)N * 4);
    float* dinv_n  = (float*)alloc((size_t)N * 4);
    float* dinv2_n = (float*)alloc((size_t)N * 4);
    int*   cnt_o   = (int*)alloc((size_t)N * 4);
    int*   cnt_n   = (int*)alloc((size_t)N * 4);
    int*   rp_o    = (int*)alloc((size_t)(N + 1) * 4);
    int*   rp_n    = (int*)alloc((size_t)(N + 1) * 4);
    int*   cur_o   = (int*)alloc((size_t)N * 4);
    int*   cur_n   = (int*)alloc((size_t)N * 4);
    int*   col_o   = (int*)alloc((size_t)E * 4);
    int*   col_n   = (int*)alloc((size_t)E * 4);
    float* val_o   = (float*)alloc((size_t)E * 4);
    float* val_n   = (float*)alloc((size_t)E * 4);
    float* Wc0o    = (float*)alloc(DIM * DIM * 4);
    float* Wc0n    = (float*)alloc(DIM * DIM * 4);
    float* Wc1o    = (float*)alloc(DIM * DIM * 4);
    float* Wc1n    = (float*)alloc(DIM * DIM * 4);
    float* bc0     = (float*)alloc(DIM * 4);
    float* bc1     = (float*)alloc(DIM * 4);
    int*   gs      = (int*)alloc(64 * 4);
    int*   ge      = (int*)alloc(64 * 4);

    hipMemsetAsync(dinv_o, 0, (size_t)N * 4, stream);
    hipMemsetAsync(dinv_n, 0, (size_t)N * 4, stream);
    hipMemsetAsync(cnt_o, 0, (size_t)N * 4, stream);
    hipMemsetAsync(cnt_n, 0, (size_t)N * 4, stream);
    hipMemsetAsync(gs, 0x7f, 64 * 4, stream);
    hipMemsetAsync(ge, 0, 64 * 4, stream);
    hipMemsetAsync(d_out, 0, (size_t)out_size * 4, stream);

    int eb = (E + 255) / 256;
    int nb = (N + 255) / 256;
    k_deg<<<eb, 256, 0, stream>>>(ei, ew, dinv_o, cnt_o, E);
    k_deg<<<eb, 256, 0, stream>>>(ein, ewn, dinv_n, cnt_n, E);
    k_dinv<<<nb, 256, 0, stream>>>(dinv_o, dinv2_o, N);
    k_dinv<<<nb, 256, 0, stream>>>(dinv_n, dinv2_n, N);
    k_scan<<<2, 1024, 0, stream>>>(cnt_o, rp_o, cur_o, cnt_n, rp_n, cur_n, N);
    k_scatter<<<eb, 256, 0, stream>>>(ei, ew, dinv_o, cur_o, col_o, val_o, E);
    k_scatter<<<eb, 256, 0, stream>>>(ein, ewn, dinv_n, cur_n, col_n, val_n, E);
    k_combine<<<36, 256, 0, stream>>>(W0o, W0n, W0f, b0o, b0n, b0f, Wc0o, Wc0n, bc0);
    k_combine<<<36, 256, 0, stream>>>(W1o, W1n, W1f, b1o, b1n, b1f, Wc1o, Wc1n, bc1);
    k_bounds<<<nb, 256, 0, stream>>>(batch, gs, ge, N);

    int ab = ((size_t)N * 64 + 255) / 256;
    int mb = (N + RB - 1) / RB;

    // layer 0
    k_agg<<<ab, 256, 0, stream>>>(x, rp_o, col_o, val_o, dinv2_o, fA, N);
    k_agg<<<ab, 256, 0, stream>>>(x, rp_n, col_n, val_n, dinv2_n, fB, N);
    k_matmul<<<mb, 192, 0, stream>>>(fA, fB, Wc0o, Wc0n, bc0, fH, N);
    k_pool<<<dim3(16, 64), 96, 0, stream>>>(fH, gs, ge, out);

    // layer 1
    k_agg<<<ab, 256, 0, stream>>>(fH, rp_o, col_o, val_o, dinv2_o, fA, N);
    k_agg<<<ab, 256, 0, stream>>>(fH, rp_n, col_n, val_n, dinv2_n, fB, N);
    k_matmul<<<mb, 192, 0, stream>>>(fA, fB, Wc1o, Wc1n, bc1, fH, N);
    k_pool<<<dim3(16, 64), 96, 0, stream>>>(fH, gs, ge, out + 64 * DIM);

    k_divide<<<(2 * 64 * DIM + 255) / 256, 256, 0, stream>>>(out, gs, ge, 2 * 64 * DIM);
}

// Round 2
// 662.826 us; speedup vs baseline: 1.2636x; 1.2636x over previous
//
#include <hip/hip_runtime.h>
#include <hip/hip_bf16.h>

#define DIM 96

// ---------------- degree + count per dst ----------------
__global__ void k_deg(const int* __restrict__ ei, const float* __restrict__ ew,
                      float* __restrict__ deg, int* __restrict__ cnt, int E) {
    int e = blockIdx.x * 256 + threadIdx.x;
    if (e >= E) return;
    int d = ei[E + e];
    atomicAdd(&deg[d], ew[e]);
    atomicAdd(&cnt[d], 1);
}

// ---------------- deg -> dinv, dinv2 (in place over deg) ----------------
__global__ void k_dinv(float* __restrict__ dinv, float* __restrict__ dinv2, int n) {
    int i = blockIdx.x * 256 + threadIdx.x;
    if (i >= n) return;
    float d = dinv[i] + 1.0f;            // +1 self loop
    float r = rsqrtf(d);
    dinv[i] = r;
    dinv2[i] = r * r;
}

// ---------------- exclusive scan (two arrays, one block each) ----------------
__global__ __launch_bounds__(1024) void k_scan(
    const int* __restrict__ cnt0, int* __restrict__ rp0, int* __restrict__ cur0,
    const int* __restrict__ cnt1, int* __restrict__ rp1, int* __restrict__ cur1, int n)
{
    const int* cnt = blockIdx.x ? cnt1 : cnt0;
    int* rp  = blockIdx.x ? rp1  : rp0;
    int* cur = blockIdx.x ? cur1 : cur0;
    __shared__ int wsum[16];
    __shared__ int carry_s;
    int tid = threadIdx.x, lane = tid & 63, wid = tid >> 6;
    if (tid == 0) { carry_s = 0; rp[0] = 0; }
    __syncthreads();
    for (int base = 0; base < n; base += 1024) {
        int i = base + tid;
        int v = (i < n) ? cnt[i] : 0;
        int xv = v;
        #pragma unroll
        for (int d = 1; d < 64; d <<= 1) {
            int t = __shfl_up(xv, d);
            if (lane >= d) xv += t;
        }
        if (lane == 63) wsum[wid] = xv;
        __syncthreads();
        if (wid == 0) {
            int y = (lane < 16) ? wsum[lane] : 0;
            #pragma unroll
            for (int d = 1; d < 16; d <<= 1) {
                int t = __shfl_up(y, d);
                if (lane >= d) y += t;
            }
            if (lane < 16) wsum[lane] = y;
        }
        __syncthreads();
        int woff = (wid > 0) ? wsum[wid - 1] : 0;
        int incl = xv + woff + carry_s;
        if (i < n) { rp[i + 1] = incl; cur[i] = incl - v; }
        __syncthreads();
        if (tid == 1023) carry_s = incl;
        __syncthreads();
    }
}

// ---------------- scatter edges into CSR (by dst) ----------------
__global__ void k_scatter(const int* __restrict__ ei, const float* __restrict__ ew,
                          const float* __restrict__ dinv, int* __restrict__ cur,
                          int* __restrict__ col, float* __restrict__ val, int E) {
    int e = blockIdx.x * 256 + threadIdx.x;
    if (e >= E) return;
    int s = ei[e];
    int d = ei[E + e];
    float w = ew[e];
    int slot = atomicAdd(&cur[d], 1);
    col[slot] = s;
    val[slot] = dinv[s] * w * dinv[d];
}

// ---------------- fold W_o@Wf_top, W_n@Wf_bot, combined bias ----------------
__global__ void k_combine(const float* __restrict__ Wo, const float* __restrict__ Wn,
                          const float* __restrict__ Wf, const float* __restrict__ bo,
                          const float* __restrict__ bn, const float* __restrict__ bf,
                          float* __restrict__ Wco, float* __restrict__ Wcn,
                          float* __restrict__ bc) {
    int g = blockIdx.x * 256 + threadIdx.x;
    if (g >= DIM * DIM) return;
    int i = g / DIM, j = g % DIM;
    float so = 0.f, sn = 0.f;
    for (int k = 0; k < DIM; ++k) {
        so += Wo[i * DIM + k] * Wf[k * DIM + j];
        sn += Wn[i * DIM + k] * Wf[(DIM + k) * DIM + j];
    }
    Wco[g] = so;
    Wcn[g] = sn;
    if (i == 0) {
        float s = bf[j];
        for (int k = 0; k < DIM; ++k) {
            s += bo[k] * Wf[k * DIM + j] + bn[k] * Wf[(DIM + k) * DIM + j];
        }
        bc[j] = s;
    }
}

// ---------------- graph boundary detection (batch is sorted) ----------------
__global__ void k_bounds(const int* __restrict__ batch, int* __restrict__ gs,
                         int* __restrict__ ge, int n) {
    int i = blockIdx.x * 256 + threadIdx.x;
    if (i >= n) return;
    int b = batch[i];
    if (i == 0 || batch[i - 1] != b) atomicMin(&gs[b], i);
    if (i == n - 1 || batch[i + 1] != b) atomicMax(&ge[b], i + 1);
}

// ---------------- aggregation (both edge sets via blockIdx.y) ----------------
// One wave per node; lanes 0..23 each own a float4 column chunk (24*4 = 96).
// Edge loop unrolled x4 with batched col/val loads -> 4 row gathers in flight.
__global__ __launch_bounds__(256) void k_agg(
    const float* __restrict__ X,
    const int* __restrict__ rp_o, const int* __restrict__ col_o,
    const float* __restrict__ val_o, const float* __restrict__ dinv2_o,
    const int* __restrict__ rp_n, const int* __restrict__ col_n,
    const float* __restrict__ val_n, const float* __restrict__ dinv2_n,
    float* __restrict__ outA, float* __restrict__ outB, int n)
{
    int wid = (blockIdx.x * 256 + threadIdx.x) >> 6;   // node id
    int lane = threadIdx.x & 63;
    if (wid >= n || lane >= 24) return;

    const int*   rp    = blockIdx.y ? rp_n    : rp_o;
    const int*   col   = blockIdx.y ? col_n   : col_o;
    const float* val   = blockIdx.y ? val_n   : val_o;
    const float* dinv2 = blockIdx.y ? dinv2_n : dinv2_o;
    float*       out   = blockIdx.y ? outB    : outA;

    const float4* Xv = (const float4*)X;
    size_t rowstride = DIM / 4;   // 24 float4 per row

    float d2 = dinv2[wid];
    float4 xs = Xv[(size_t)wid * rowstride + lane];
    float4 acc;
    acc.x = d2 * xs.x; acc.y = d2 * xs.y; acc.z = d2 * xs.z; acc.w = d2 * xs.w;

    int s = rp[wid], e = rp[wid + 1];
    int j = s;
    for (; j + 4 <= e; j += 4) {
        int u0 = col[j], u1 = col[j + 1], u2 = col[j + 2], u3 = col[j + 3];
        float w0 = val[j], w1 = val[j + 1], w2 = val[j + 2], w3 = val[j + 3];
        float4 x0 = Xv[(size_t)u0 * rowstride + lane];
        float4 x1 = Xv[(size_t)u1 * rowstride + lane];
        float4 x2 = Xv[(size_t)u2 * rowstride + lane];
        float4 x3 = Xv[(size_t)u3 * rowstride + lane];
        acc.x += w0 * x0.x; acc.y += w0 * x0.y; acc.z += w0 * x0.z; acc.w += w0 * x0.w;
        acc.x += w1 * x1.x; acc.y += w1 * x1.y; acc.z += w1 * x1.z; acc.w += w1 * x1.w;
        acc.x += w2 * x2.x; acc.y += w2 * x2.y; acc.z += w2 * x2.z; acc.w += w2 * x2.w;
        acc.x += w3 * x3.x; acc.y += w3 * x3.y; acc.z += w3 * x3.z; acc.w += w3 * x3.w;
    }
    for (; j < e; ++j) {
        int u = col[j];
        float w = val[j];
        float4 xv = Xv[(size_t)u * rowstride + lane];
        acc.x += w * xv.x; acc.y += w * xv.y; acc.z += w * xv.z; acc.w += w * xv.w;
    }
    ((float4*)out)[(size_t)wid * rowstride + lane] = acc;
}

// ---------------- out = relu(A@Wo + B@Wn + bias) ----------------
#define RB 24
__global__ __launch_bounds__(192) void k_matmul(
    const float* __restrict__ A, const float* __restrict__ B,
    const float* __restrict__ Wo, const float* __restrict__ Wn,
    const float* __restrict__ bias, float* __restrict__ out, int n)
{
    __shared__ float lA[RB * 100];
    __shared__ float lB[RB * 100];
    __shared__ float lW[2][32 * DIM];
    int tid = threadIdx.x;
    int r0 = blockIdx.x * RB;
    int rows = min(RB, n - r0);
    int limit = rows * DIM;
    #pragma unroll
    for (int j = 0; j < 3; ++j) {
        int o = (tid + j * 192) * 4;
        float4 va = make_float4(0.f, 0.f, 0.f, 0.f), vb = va;
        if (o < limit) {
            va = *(const float4*)(A + (size_t)r0 * DIM + o);
            vb = *(const float4*)(B + (size_t)r0 * DIM + o);
        }
        int r = o / DIM, c = o % DIM;
        *(float4*)&lA[r * 100 + c] = va;
        *(float4*)&lB[r * 100 + c] = vb;
    }
    int cg = tid % 24, rg = tid / 24;       // 24 col-groups x 8 row-groups
    float acc[3][4] = {};
    for (int kc = 0; kc < DIM; kc += 32) {
        __syncthreads();
        #pragma unroll
        for (int j = 0; j < 4; ++j) {
            int o = (tid + j * 192) * 4;
            *(float4*)&lW[0][o] = *(const float4*)(Wo + kc * DIM + o);
            *(float4*)&lW[1][o] = *(const float4*)(Wn + kc * DIM + o);
        }
        __syncthreads();
        for (int k = 0; k < 32; ++k) {
            float4 wo = *(const float4*)&lW[0][k * DIM + cg * 4];
            float4 wn = *(const float4*)&lW[1][k * DIM + cg * 4];
            int kk = kc + k;
            #pragma unroll
            for (int r = 0; r < 3; ++r) {
                float a = lA[(rg * 3 + r) * 100 + kk];
                float b = lB[(rg * 3 + r) * 100 + kk];
                acc[r][0] += a * wo.x + b * wn.x;
                acc[r][1] += a * wo.y + b * wn.y;
                acc[r][2] += a * wo.z + b * wn.z;
                acc[r][3] += a * wo.w + b * wn.w;
            }
        }
    }
    int cb = cg * 4;
    float4 bs = *(const float4*)(bias + cb);
    #pragma unroll
    for (int r = 0; r < 3; ++r) {
        int row = rg * 3 + r;
        if (row < rows) {
            float4 v;
            v.x = fmaxf(acc[r][0] + bs.x, 0.f);
            v.y = fmaxf(acc[r][1] + bs.y, 0.f);
            v.z = fmaxf(acc[r][2] + bs.z, 0.f);
            v.w = fmaxf(acc[r][3] + bs.w, 0.f);
            *(float4*)(out + (size_t)(r0 + row) * DIM + cb) = v;
        }
    }
}

// ---------------- mean pool: partial sums + atomic ----------------
__global__ void k_pool(const float* __restrict__ X, const int* __restrict__ gs,
                       const int* __restrict__ ge, float* __restrict__ outp) {
    int g = blockIdx.y;
    int c = threadIdx.x;       // 96 threads
    float acc = 0.f;
    int s = gs[g], e = ge[g];
    for (int i = s + blockIdx.x; i < e; i += gridDim.x) {
        acc += X[(size_t)i * DIM + c];
    }
    atomicAdd(&outp[g * DIM + c], acc);
}

__global__ void k_divide(float* __restrict__ out, const int* __restrict__ gs,
                         const int* __restrict__ ge, int total) {
    int idx = blockIdx.x * 256 + threadIdx.x;
    if (idx >= total) return;
    int g = (idx / DIM) % 64;
    int c = ge[g] - gs[g];
    if (c < 1) c = 1;
    out[idx] /= (float)c;
}

extern "C" void kernel_launch(void* const* d_in, const int* in_sizes, int n_in,
                              void* d_out, int out_size, void* d_ws, size_t ws_size,
                              hipStream_t stream)
{
    const float* x     = (const float*)d_in[0];
    const int*   ei    = (const int*)d_in[1];
    const float* ew    = (const float*)d_in[2];
    const int*   batch = (const int*)d_in[3];
    const int*   ein   = (const int*)d_in[4];
    const float* ewn   = (const float*)d_in[5];
    const float* W0o = (const float*)d_in[7];
    const float* b0o = (const float*)d_in[8];
    const float* W0n = (const float*)d_in[9];
    const float* b0n = (const float*)d_in[10];
    const float* W0f = (const float*)d_in[11];
    const float* b0f = (const float*)d_in[12];
    const float* W1o = (const float*)d_in[13];
    const float* b1o = (const float*)d_in[14];
    const float* W1n = (const float*)d_in[15];
    const float* b1n = (const float*)d_in[16];
    const float* W1f = (const float*)d_in[17];
    const float* b1f = (const float*)d_in[18];

    const int N = in_sizes[0] / DIM;
    const int E = in_sizes[2];
    float* out = (float*)d_out;

    char* ws = (char*)d_ws;
    size_t off = 0;
    auto alloc = [&](size_t bytes) -> char* {
        char* p = ws + off;
        off += (bytes + 255) & ~(size_t)255;
        return p;
    };
    float* fA      = (float*)alloc((size_t)N * DIM * 4);
    float* fB      = (float*)alloc((size_t)N * DIM * 4);
    float* fH      = (float*)alloc((size_t)N * DIM * 4);
    float* dinv_o  = (float*)alloc((size_t)N * 4);     // also deg storage
    float* dinv2_o = (float*)alloc((size_t)N * 4);
    float* dinv_n  = (float*)alloc((size_t)N * 4);
    float* dinv2_n = (float*)alloc((size_t)N * 4);
    int*   cnt_o   = (int*)alloc((size_t)N * 4);
    int*   cnt_n   = (int*)alloc((size_t)N * 4);
    int*   rp_o    = (int*)alloc((size_t)(N + 1) * 4);
    int*   rp_n    = (int*)alloc((size_t)(N + 1) * 4);
    int*   cur_o   = (int*)alloc((size_t)N * 4);
    int*   cur_n   = (int*)alloc((size_t)N * 4);
    int*   col_o   = (int*)alloc((size_t)E * 4);
    int*   col_n   = (int*)alloc((size_t)E * 4);
    float* val_o   = (float*)alloc((size_t)E * 4);
    float* val_n   = (float*)alloc((size_t)E * 4);
    float* Wc0o    = (float*)alloc(DIM * DIM * 4);
    float* Wc0n    = (float*)alloc(DIM * DIM * 4);
    float* Wc1o    = (float*)alloc(DIM * DIM * 4);
    float* Wc1n    = (float*)alloc(DIM * DIM * 4);
    float* bc0     = (float*)alloc(DIM * 4);
    float* bc1     = (float*)alloc(DIM * 4);
    int*   gs      = (int*)alloc(64 * 4);
    int*   ge      = (int*)alloc(64 * 4);

    hipMemsetAsync(dinv_o, 0, (size_t)N * 4, stream);
    hipMemsetAsync(dinv_n, 0, (size_t)N * 4, stream);
    hipMemsetAsync(cnt_o, 0, (size_t)N * 4, stream);
    hipMemsetAsync(cnt_n, 0, (size_t)N * 4, stream);
    hipMemsetAsync(gs, 0x7f, 64 * 4, stream);
    hipMemsetAsync(ge, 0, 64 * 4, stream);
    hipMemsetAsync(d_out, 0, (size_t)out_size * 4, stream);

    int eb = (E + 255) / 256;
    int nb = (N + 255) / 256;
    k_deg<<<eb, 256, 0, stream>>>(ei, ew, dinv_o, cnt_o, E);
    k_deg<<<eb, 256, 0, stream>>>(ein, ewn, dinv_n, cnt_n, E);
    k_dinv<<<nb, 256, 0, stream>>>(dinv_o, dinv2_o, N);
    k_dinv<<<nb, 256, 0, stream>>>(dinv_n, dinv2_n, N);
    k_scan<<<2, 1024, 0, stream>>>(cnt_o, rp_o, cur_o, cnt_n, rp_n, cur_n, N);
    k_scatter<<<eb, 256, 0, stream>>>(ei, ew, dinv_o, cur_o, col_o, val_o, E);
    k_scatter<<<eb, 256, 0, stream>>>(ein, ewn, dinv_n, cur_n, col_n, val_n, E);
    k_combine<<<36, 256, 0, stream>>>(W0o, W0n, W0f, b0o, b0n, b0f, Wc0o, Wc0n, bc0);
    k_combine<<<36, 256, 0, stream>>>(W1o, W1n, W1f, b1o, b1n, b1f, Wc1o, Wc1n, bc1);
    k_bounds<<<nb, 256, 0, stream>>>(batch, gs, ge, N);

    dim3 ag(((size_t)N * 64 + 255) / 256, 2);
    int mb = (N + RB - 1) / RB;

    // layer 0
    k_agg<<<ag, 256, 0, stream>>>(x, rp_o, col_o, val_o, dinv2_o,
                                  rp_n, col_n, val_n, dinv2_n, fA, fB, N);
    k_matmul<<<mb, 192, 0, stream>>>(fA, fB, Wc0o, Wc0n, bc0, fH, N);
    k_pool<<<dim3(16, 64), 96, 0, stream>>>(fH, gs, ge, out);

    // layer 1
    k_agg<<<ag, 256, 0, stream>>>(fH, rp_o, col_o, val_o, dinv2_o,
                                  rp_n, col_n, val_n, dinv2_n, fA, fB, N);
    k_matmul<<<mb, 192, 0, stream>>>(fA, fB, Wc1o, Wc1n, bc1, fH, N);
    k_pool<<<dim3(16, 64), 96, 0, stream>>>(fH, gs, ge, out + 64 * DIM);

    k_divide<<<(2 * 64 * DIM + 255) / 256, 256, 0, stream>>>(out, gs, ge, 2 * 64 * DIM);
}

// Round 3
// 523.235 us; speedup vs baseline: 1.6007x; 1.2668x over previous
//
#include <hip/hip_runtime.h>
#include <hip/hip_bf16.h>

#define DIM 96
typedef unsigned int u32;

__device__ __forceinline__ u32 bfr(float f) {           // f32 -> bf16 bits (RNE)
    u32 b = __float_as_uint(f);
    return (b + 0x7fffu + ((b >> 16) & 1u)) >> 16;
}
__device__ __forceinline__ u32 pk2(float lo, float hi) { return bfr(lo) | (bfr(hi) << 16); }
__device__ __forceinline__ float bl(u32 u) { return __uint_as_float(u << 16); }
__device__ __forceinline__ float bh(u32 u) { return __uint_as_float(u & 0xffff0000u); }

struct __align__(4) U3 { u32 a, b, c; };

// ---------------- init: zero deg/cnt zone + d_out, set gs/ge ----------------
__global__ void k_init(u32* __restrict__ zone, float* __restrict__ outp,
                       int* __restrict__ gs, int* __restrict__ ge, int n4, int osz) {
    int i = blockIdx.x * 256 + threadIdx.x;
    if (i < n4) zone[i] = 0;
    int j = i - n4;
    if (j >= 0 && j < osz) outp[j] = 0.f;
    int k2 = j - osz;
    if (k2 >= 0 && k2 < 64) gs[k2] = 0x7fffffff;
    int k3 = k2 - 64;
    if (k3 >= 0 && k3 < 64) ge[k3] = 0;
}

// ---------------- degree + count per dst (both edge sets) ----------------
__global__ void k_deg(const int* __restrict__ ei, const float* __restrict__ ew,
                      const int* __restrict__ ein, const float* __restrict__ ewn,
                      float* __restrict__ deg, int* __restrict__ cnt, int E, int n) {
    int e = blockIdx.x * 256 + threadIdx.x;
    if (e >= E) return;
    const int*   I = blockIdx.y ? ein : ei;
    const float* W = blockIdx.y ? ewn : ew;
    float* dg = deg + (blockIdx.y ? n : 0);
    int*   cn = cnt + (blockIdx.y ? n : 0);
    int d = I[E + e];
    atomicAdd(&dg[d], W[e]);
    atomicAdd(&cn[d], 1);
}

// ---------------- deg -> dinv, dinv2 over 2N ----------------
__global__ void k_dinv(const float* __restrict__ deg, float* __restrict__ dinv,
                       float* __restrict__ dinv2, int n2) {
    int i = blockIdx.x * 256 + threadIdx.x;
    if (i >= n2) return;
    float d = deg[i] + 1.0f;
    float r = rsqrtf(d);
    dinv[i] = r;
    dinv2[i] = r * r;
}

// ---------------- exclusive scan, 8 elems/thread, one block per edge set ----------------
__global__ __launch_bounds__(1024) void k_scan(
    const int* __restrict__ cnt0, int* __restrict__ st0, int* __restrict__ cur0,
    const int* __restrict__ cnt1, int* __restrict__ st1, int* __restrict__ cur1, int n)
{
    const int* cnt = blockIdx.x ? cnt1 : cnt0;
    int* st  = blockIdx.x ? st1 : st0;
    int* cur = blockIdx.x ? cur1 : cur0;
    __shared__ int wsum[16];
    __shared__ int carry_s;
    int tid = threadIdx.x, lane = tid & 63, wid = tid >> 6;
    if (tid == 0) carry_s = 0;
    __syncthreads();
    for (int base = 0; base < n; base += 8192) {
        int i0 = base + tid * 8;
        int v[8];
        if (i0 + 8 <= n) {
            int4 a = *(const int4*)(cnt + i0);
            int4 b = *(const int4*)(cnt + i0 + 4);
            v[0]=a.x; v[1]=a.y; v[2]=a.z; v[3]=a.w;
            v[4]=b.x; v[5]=b.y; v[6]=b.z; v[7]=b.w;
        } else {
            #pragma unroll
            for (int k = 0; k < 8; ++k) v[k] = (i0 + k < n) ? cnt[i0 + k] : 0;
        }
        int s[8]; int run = 0;
        #pragma unroll
        for (int k = 0; k < 8; ++k) { run += v[k]; s[k] = run; }
        int tsum = run, winc = tsum;
        #pragma unroll
        for (int d = 1; d < 64; d <<= 1) {
            int t = __shfl_up(winc, d);
            if (lane >= d) winc += t;
        }
        if (lane == 63) wsum[wid] = winc;
        __syncthreads();
        if (wid == 0) {
            int y = (lane < 16) ? wsum[lane] : 0;
            #pragma unroll
            for (int d = 1; d < 16; d <<= 1) {
                int t = __shfl_up(y, d);
                if (lane >= d) y += t;
            }
            if (lane < 16) wsum[lane] = y;
        }
        __syncthreads();
        int woff = (wid > 0) ? wsum[wid - 1] : 0;
        int tbase = carry_s + woff + winc - tsum;     // exclusive base for this thread
        if (i0 < n) {
            if (i0 + 8 <= n) {
                int4 e0, e1;
                e0.x = tbase + s[0]-v[0]; e0.y = tbase + s[1]-v[1];
                e0.z = tbase + s[2]-v[2]; e0.w = tbase + s[3]-v[3];
                e1.x = tbase + s[4]-v[4]; e1.y = tbase + s[5]-v[5];
                e1.z = tbase + s[6]-v[6]; e1.w = tbase + s[7]-v[7];
                *(int4*)(st + i0) = e0;  *(int4*)(st + i0 + 4) = e1;
                *(int4*)(cur + i0) = e0; *(int4*)(cur + i0 + 4) = e1;
            } else {
                for (int k = 0; k < 8; ++k) {
                    if (i0 + k < n) { int ex = tbase + s[k]-v[k]; st[i0+k] = ex; cur[i0+k] = ex; }
                }
            }
        }
        __syncthreads();
        if (tid == 0) carry_s += wsum[15];
        __syncthreads();
    }
}

// ---------------- scatter edges into CSR (both sets) ----------------
__global__ void k_scatter(const int* __restrict__ ei, const float* __restrict__ ew,
                          const int* __restrict__ ein, const float* __restrict__ ewn,
                          const float* __restrict__ dinv,
                          int* __restrict__ cur_o, int* __restrict__ cur_n,
                          int* __restrict__ col_o, float* __restrict__ val_o,
                          int* __restrict__ col_n, float* __restrict__ val_n,
                          int E, int n) {
    int e = blockIdx.x * 256 + threadIdx.x;
    if (e >= E) return;
    const int*   I = blockIdx.y ? ein : ei;
    const float* W = blockIdx.y ? ewn : ew;
    const float* dv = dinv + (blockIdx.y ? n : 0);
    int*   cur = blockIdx.y ? cur_n : cur_o;
    int*   col = blockIdx.y ? col_n : col_o;
    float* val = blockIdx.y ? val_n : val_o;
    int s = I[e], d = I[E + e];
    float w = W[e];
    int slot = atomicAdd(&cur[d], 1);
    col[slot] = s;
    val[slot] = dv[s] * w * dv[d];
}

// ---------------- graph boundary detection ----------------
__global__ void k_bounds(const int* __restrict__ batch, int* __restrict__ gs,
                         int* __restrict__ ge, int n) {
    int i = blockIdx.x * 256 + threadIdx.x;
    if (i >= n) return;
    int b = batch[i];
    if (i == 0 || batch[i - 1] != b) atomicMin(&gs[b], i);
    if (i == n - 1 || batch[i + 1] != b) atomicMax(&ge[b], i + 1);
}

// ---------------- combined weights (both layers) + rinv tail ----------------
__global__ void k_combine(
    const float* __restrict__ W0o, const float* __restrict__ W0n, const float* __restrict__ W0f,
    const float* __restrict__ b0o, const float* __restrict__ b0n, const float* __restrict__ b0f,
    const float* __restrict__ W1o, const float* __restrict__ W1n, const float* __restrict__ W1f,
    const float* __restrict__ b1o, const float* __restrict__ b1n, const float* __restrict__ b1f,
    float* __restrict__ Wc0o, float* __restrict__ Wc0n, float* __restrict__ bc0,
    float* __restrict__ Wc1o, float* __restrict__ Wc1n, float* __restrict__ bc1,
    const int* __restrict__ gs, const int* __restrict__ ge, float* __restrict__ rinv)
{
    if (blockIdx.y == 0 && blockIdx.x == 0 && threadIdx.x < 64) {
        int c = ge[threadIdx.x] - gs[threadIdx.x];
        if (c < 1) c = 1;
        rinv[threadIdx.x] = 1.0f / (float)c;
    }
    const float* Wo = blockIdx.y ? W1o : W0o;
    const float* Wn = blockIdx.y ? W1n : W0n;
    const float* Wf = blockIdx.y ? W1f : W0f;
    const float* bo = blockIdx.y ? b1o : b0o;
    const float* bn = blockIdx.y ? b1n : b0n;
    const float* bf = blockIdx.y ? b1f : b0f;
    float* Wco = blockIdx.y ? Wc1o : Wc0o;
    float* Wcn = blockIdx.y ? Wc1n : Wc0n;
    float* bc  = blockIdx.y ? bc1  : bc0;
    int g = blockIdx.x * 256 + threadIdx.x;
    if (g >= DIM * DIM) return;
    int i = g / DIM, j = g % DIM;
    float so = 0.f, sn = 0.f;
    for (int k = 0; k < DIM; ++k) {
        so += Wo[i * DIM + k] * Wf[k * DIM + j];
        sn += Wn[i * DIM + k] * Wf[(DIM + k) * DIM + j];
    }
    Wco[g] = so;
    Wcn[g] = sn;
    if (i == 0) {
        float s = bf[j];
        for (int k = 0; k < DIM; ++k)
            s += bo[k] * Wf[k * DIM + j] + bn[k] * Wf[(DIM + k) * DIM + j];
        bc[j] = s;
    }
}

// ---------------- cast x (f32) -> packed bf16 ----------------
__global__ void k_cast(const float* __restrict__ x, u32* __restrict__ Xh, int total8) {
    int i = blockIdx.x * 256 + threadIdx.x;
    if (i >= total8) return;
    const float4* xv = (const float4*)x;
    float4 a = xv[i * 2], b = xv[i * 2 + 1];
    uint4 o;
    o.x = pk2(a.x, a.y); o.y = pk2(a.z, a.w);
    o.z = pk2(b.x, b.y); o.w = pk2(b.z, b.w);
    ((uint4*)Xh)[i] = o;
}

// ---------------- aggregation: bf16 gather, 4 edge-groups of 16 lanes ----------------
__global__ __launch_bounds__(256) void k_agg(
    const u32* __restrict__ Xh,
    const int* __restrict__ st_o, const int* __restrict__ en_o,
    const int* __restrict__ col_o, const float* __restrict__ val_o,
    const int* __restrict__ st_n, const int* __restrict__ en_n,
    const int* __restrict__ col_n, const float* __restrict__ val_n,
    const float* __restrict__ dinv2,
    float* __restrict__ outA, float* __restrict__ outB, int n)
{
    int wid = (blockIdx.x * 256 + threadIdx.x) >> 6;
    if (wid >= n) return;
    int lane = threadIdx.x & 63;
    int g = lane >> 4, sl = lane & 15;
    const int* st; const int* en; const int* col; const float* val; const float* d2p; float* out;
    if (blockIdx.y) { st = st_n; en = en_n; col = col_n; val = val_n; d2p = dinv2 + n; out = outB; }
    else            { st = st_o; en = en_o; col = col_o; val = val_o; d2p = dinv2;     out = outA; }

    float a0=0,a1=0,a2=0,a3=0,a4=0,a5=0;
    if (g == 0) {
        float d2 = d2p[wid];
        U3 xv = *(const U3*)(Xh + (size_t)wid * 48 + sl * 3);
        a0 = d2 * bl(xv.a); a1 = d2 * bh(xv.a);
        a2 = d2 * bl(xv.b); a3 = d2 * bh(xv.b);
        a4 = d2 * bl(xv.c); a5 = d2 * bh(xv.c);
    }
    int s = st[wid], e = en[wid];
    int j = s + g;
    for (; j + 4 < e; j += 8) {
        int u0 = col[j], u1 = col[j + 4];
        float w0 = val[j], w1 = val[j + 4];
        U3 x0 = *(const U3*)(Xh + (size_t)u0 * 48 + sl * 3);
        U3 x1 = *(const U3*)(Xh + (size_t)u1 * 48 + sl * 3);
        a0 += w0 * bl(x0.a); a1 += w0 * bh(x0.a);
        a2 += w0 * bl(x0.b); a3 += w0 * bh(x0.b);
        a4 += w0 * bl(x0.c); a5 += w0 * bh(x0.c);
        a0 += w1 * bl(x1.a); a1 += w1 * bh(x1.a);
        a2 += w1 * bl(x1.b); a3 += w1 * bh(x1.b);
        a4 += w1 * bl(x1.c); a5 += w1 * bh(x1.c);
    }
    for (; j < e; j += 4) {
        int u = col[j];
        float w = val[j];
        U3 xv = *(const U3*)(Xh + (size_t)u * 48 + sl * 3);
        a0 += w * bl(xv.a); a1 += w * bh(xv.a);
        a2 += w * bl(xv.b); a3 += w * bh(xv.b);
        a4 += w * bl(xv.c); a5 += w * bh(xv.c);
    }
    a0 += __shfl_xor(a0, 32); a1 += __shfl_xor(a1, 32); a2 += __shfl_xor(a2, 32);
    a3 += __shfl_xor(a3, 32); a4 += __shfl_xor(a4, 32); a5 += __shfl_xor(a5, 32);
    a0 += __shfl_xor(a0, 16); a1 += __shfl_xor(a1, 16); a2 += __shfl_xor(a2, 16);
    a3 += __shfl_xor(a3, 16); a4 += __shfl_xor(a4, 16); a5 += __shfl_xor(a5, 16);
    if (g == 0) {
        float2* O = (float2*)(out + (size_t)wid * DIM + sl * 6);
        float2 t;
        t.x = a0; t.y = a1; O[0] = t;
        t.x = a2; t.y = a3; O[1] = t;
        t.x = a4; t.y = a5; O[2] = t;
    }
}

// ---------------- H = relu(A@Wo + B@Wn + b); fused mean-pool; bf16 H write ----------------
#define RB 24
__global__ __launch_bounds__(192) void k_mmp(
    const float* __restrict__ A, const float* __restrict__ B,
    const float* __restrict__ Wo, const float* __restrict__ Wn,
    const float* __restrict__ bias, const int* __restrict__ batch,
    const float* __restrict__ rinv, float* __restrict__ outp,
    u32* __restrict__ Hh, int writeH, int n)
{
    __shared__ float lA[RB * 100];
    __shared__ float lB[RB * 100];
    __shared__ float lW[2][32 * DIM];
    __shared__ float pool[8 * DIM];
    int tid = threadIdx.x;
    int r0 = blockIdx.x * RB;
    int rows = min(RB, n - r0);
    int limit = rows * DIM;
    #pragma unroll
    for (int j = 0; j < 3; ++j) {
        int o = (tid + j * 192) * 4;
        float4 va = make_float4(0.f, 0.f, 0.f, 0.f), vb = va;
        if (o < limit) {
            va = *(const float4*)(A + (size_t)r0 * DIM + o);
            vb = *(const float4*)(B + (size_t)r0 * DIM + o);
        }
        int r = o / DIM, c = o % DIM;
        *(float4*)&lA[r * 100 + c] = va;
        *(float4*)&lB[r * 100 + c] = vb;
    }
    int cg = tid % 24, rg = tid / 24;
    float acc[3][4] = {};
    for (int kc = 0; kc < DIM; kc += 32) {
        __syncthreads();
        #pragma unroll
        for (int j = 0; j < 4; ++j) {
            int o = (tid + j * 192) * 4;
            *(float4*)&lW[0][o] = *(const float4*)(Wo + kc * DIM + o);
            *(float4*)&lW[1][o] = *(const float4*)(Wn + kc * DIM + o);
        }
        __syncthreads();
        for (int k = 0; k < 32; ++k) {
            float4 wo = *(const float4*)&lW[0][k * DIM + cg * 4];
            float4 wn = *(const float4*)&lW[1][k * DIM + cg * 4];
            int kk = kc + k;
            #pragma unroll
            for (int r = 0; r < 3; ++r) {
                float a = lA[(rg * 3 + r) * 100 + kk];
                float b = lB[(rg * 3 + r) * 100 + kk];
                acc[r][0] += a * wo.x + b * wn.x;
                acc[r][1] += a * wo.y + b * wn.y;
                acc[r][2] += a * wo.z + b * wn.z;
                acc[r][3] += a * wo.w + b * wn.w;
            }
        }
    }
    int cb = cg * 4;
    float4 bs = *(const float4*)(bias + cb);
    int g0 = batch[r0];
    int gL = batch[r0 + rows - 1];
    bool fast = (g0 == gL);
    float p0 = 0.f, p1 = 0.f, p2 = 0.f, p3 = 0.f;
    #pragma unroll
    for (int r = 0; r < 3; ++r) {
        int row = rg * 3 + r;
        if (row < rows) {
            float vx = fmaxf(acc[r][0] + bs.x, 0.f);
            float vy = fmaxf(acc[r][1] + bs.y, 0.f);
            float vz = fmaxf(acc[r][2] + bs.z, 0.f);
            float vw = fmaxf(acc[r][3] + bs.w, 0.f);
            int grow = r0 + row;
            if (writeH) {
                uint2 h; h.x = pk2(vx, vy); h.y = pk2(vz, vw);
                ((uint2*)Hh)[(size_t)grow * 24 + cg] = h;
            }
            if (fast) { p0 += vx; p1 += vy; p2 += vz; p3 += vw; }
            else {
                int gg = batch[grow];
                float rv = rinv[gg];
                atomicAdd(&outp[gg * DIM + cb + 0], vx * rv);
                atomicAdd(&outp[gg * DIM + cb + 1], vy * rv);
                atomicAdd(&outp[gg * DIM + cb + 2], vz * rv);
                atomicAdd(&outp[gg * DIM + cb + 3], vw * rv);
            }
        }
    }
    if (fast) {
        pool[rg * DIM + cb + 0] = p0;
        pool[rg * DIM + cb + 1] = p1;
        pool[rg * DIM + cb + 2] = p2;
        pool[rg * DIM + cb + 3] = p3;
        __syncthreads();
        if (tid < DIM) {
            float s2 = 0.f;
            #pragma unroll
            for (int r2 = 0; r2 < 8; ++r2) s2 += pool[r2 * DIM + tid];
            atomicAdd(&outp[g0 * DIM + tid], s2 * rinv[g0]);
        }
    }
}

extern "C" void kernel_launch(void* const* d_in, const int* in_sizes, int n_in,
                              void* d_out, int out_size, void* d_ws, size_t ws_size,
                              hipStream_t stream)
{
    const float* x     = (const float*)d_in[0];
    const int*   ei    = (const int*)d_in[1];
    const float* ew    = (const float*)d_in[2];
    const int*   batch = (const int*)d_in[3];
    const int*   ein   = (const int*)d_in[4];
    const float* ewn   = (const float*)d_in[5];
    const float* W0o = (const float*)d_in[7];
    const float* b0o = (const float*)d_in[8];
    const float* W0n = (const float*)d_in[9];
    const float* b0n = (const float*)d_in[10];
    const float* W0f = (const float*)d_in[11];
    const float* b0f = (const float*)d_in[12];
    const float* W1o = (const float*)d_in[13];
    const float* b1o = (const float*)d_in[14];
    const float* W1n = (const float*)d_in[15];
    const float* b1n = (const float*)d_in[16];
    const float* W1f = (const float*)d_in[17];
    const float* b1f = (const float*)d_in[18];

    const int N = in_sizes[0] / DIM;
    const int E = in_sizes[2];
    float* out = (float*)d_out;

    char* ws = (char*)d_ws;
    size_t off = 0;
    auto alloc = [&](size_t bytes) -> char* {
        char* p = ws + off;
        off += (bytes + 255) & ~(size_t)255;
        return p;
    };
    u32*   zone  = (u32*)alloc((size_t)4 * N * 4);   // deg_o,deg_n (f32) | cnt_o,cnt_n (int)
    float* dinv  = (float*)alloc((size_t)2 * N * 4);
    float* dinv2 = (float*)alloc((size_t)2 * N * 4);
    int*   st_o  = (int*)alloc((size_t)N * 4);
    int*   st_n  = (int*)alloc((size_t)N * 4);
    int*   cur_o = (int*)alloc((size_t)N * 4);
    int*   cur_n = (int*)alloc((size_t)N * 4);
    int*   col_o = (int*)alloc((size_t)E * 4);
    int*   col_n = (int*)alloc((size_t)E * 4);
    float* val_o = (float*)alloc((size_t)E * 4);
    float* val_n = (float*)alloc((size_t)E * 4);
    u32*   Xh    = (u32*)alloc((size_t)N * 48 * 4);
    u32*   Hh    = (u32*)alloc((size_t)N * 48 * 4);
    float* fA    = (float*)alloc((size_t)N * DIM * 4);
    float* fB    = (float*)alloc((size_t)N * DIM * 4);
    float* Wc0o  = (float*)alloc(DIM * DIM * 4);
    float* Wc0n  = (float*)alloc(DIM * DIM * 4);
    float* Wc1o  = (float*)alloc(DIM * DIM * 4);
    float* Wc1n  = (float*)alloc(DIM * DIM * 4);
    float* bc0   = (float*)alloc(DIM * 4);
    float* bc1   = (float*)alloc(DIM * 4);
    float* rinv  = (float*)alloc(64 * 4);
    int*   gs    = (int*)alloc(64 * 4);
    int*   ge    = (int*)alloc(64 * 4);

    float* deg  = (float*)zone;
    int*   cnt  = (int*)(zone + 2 * (size_t)N);

    int eb = (E + 255) / 256;
    int nb = (N + 255) / 256;

    int initTot = 4 * N + out_size + 128;
    k_init<<<(initTot + 255) / 256, 256, 0, stream>>>(zone, out, gs, ge, 4 * N, out_size);
    k_deg<<<dim3(eb, 2), 256, 0, stream>>>(ei, ew, ein, ewn, deg, cnt, E, N);
    k_dinv<<<(2 * N + 255) / 256, 256, 0, stream>>>(deg, dinv, dinv2, 2 * N);
    k_bounds<<<nb, 256, 0, stream>>>(batch, gs, ge, N);
    k_scan<<<2, 1024, 0, stream>>>(cnt, st_o, cur_o, cnt + N, st_n, cur_n, N);
    k_scatter<<<dim3(eb, 2), 256, 0, stream>>>(ei, ew, ein, ewn, dinv,
                                               cur_o, cur_n, col_o, val_o, col_n, val_n, E, N);
    k_combine<<<dim3(36, 2), 256, 0, stream>>>(W0o, W0n, W0f, b0o, b0n, b0f,
                                               W1o, W1n, W1f, b1o, b1n, b1f,
                                               Wc0o, Wc0n, bc0, Wc1o, Wc1n, bc1,
                                               gs, ge, rinv);
    k_cast<<<(N * 12 + 255) / 256, 256, 0, stream>>>(x, Xh, N * 12);

    dim3 ag((N * 64 + 255) / 256, 2);
    int mb = (N + RB - 1) / RB;

    // layer 0
    k_agg<<<ag, 256, 0, stream>>>(Xh, st_o, cur_o, col_o, val_o,
                                  st_n, cur_n, col_n, val_n, dinv2, fA, fB, N);
    k_mmp<<<mb, 192, 0, stream>>>(fA, fB, Wc0o, Wc0n, bc0, batch, rinv, out, Hh, 1, N);
    // layer 1
    k_agg<<<ag, 256, 0, stream>>>(Hh, st_o, cur_o, col_o, val_o,
                                  st_n, cur_n, col_n, val_n, dinv2, fA, fB, N);
    k_mmp<<<mb, 192, 0, stream>>>(fA, fB, Wc1o, Wc1n, bc1, batch, rinv, out + 64 * DIM, Hh, 0, N);
}

// Round 4
// 380.619 us; speedup vs baseline: 2.2005x; 1.3747x over previous
//
#include <hip/hip_runtime.h>
#include <hip/hip_bf16.h>

#define DIM 96
typedef unsigned int u32;
typedef unsigned long long u64;

__device__ __forceinline__ u32 bfr(float f) {           // f32 -> bf16 bits (RNE)
    u32 b = __float_as_uint(f);
    return (b + 0x7fffu + ((b >> 16) & 1u)) >> 16;
}
__device__ __forceinline__ u32 pk2(float lo, float hi) { return bfr(lo) | (bfr(hi) << 16); }
__device__ __forceinline__ float bl(u32 u) { return __uint_as_float(u << 16); }
__device__ __forceinline__ float bh(u32 u) { return __uint_as_float(u & 0xffff0000u); }

struct __align__(4) U3 { u32 a, b, c; };

// ---------------- init: zero packed deg/cnt zone + d_out, set gs/ge ----------------
__global__ void k_init(u32* __restrict__ zone, float* __restrict__ outp,
                       int* __restrict__ gs, int* __restrict__ ge, int n4, int osz) {
    int i = blockIdx.x * 256 + threadIdx.x;
    if (i < n4) zone[i] = 0;
    int j = i - n4;
    if (j >= 0 && j < osz) outp[j] = 0.f;
    int k2 = j - osz;
    if (k2 >= 0 && k2 < 64) gs[k2] = 0x7fffffff;
    int k3 = k2 - 64;
    if (k3 >= 0 && k3 < 64) ge[k3] = 0;
}

// ---------------- packed degree+count, one u64 atomic per edge; rank out ----------------
__global__ void k_deg(const int* __restrict__ ei, const float* __restrict__ ew,
                      const int* __restrict__ ein, const float* __restrict__ ewn,
                      u64* __restrict__ packed, u32* __restrict__ rank_o,
                      u32* __restrict__ rank_n, int E, int n) {
    int e = blockIdx.x * 256 + threadIdx.x;
    if (e >= E) return;
    const int*   I = blockIdx.y ? ein : ei;
    const float* W = blockIdx.y ? ewn : ew;
    u64* pk = packed + (blockIdx.y ? n : 0);
    u32* rk = blockIdx.y ? rank_n : rank_o;
    int d = I[E + e];
    u32 wfix = (u32)(W[e] * 16777216.0f + 0.5f);
    u64 old = atomicAdd(&pk[d], ((u64)1 << 32) | (u64)wfix);
    rk[e] = (u32)(old >> 32);
}

// ---------------- packed -> dinv, dinv2 over 2N; graph bounds for i < N ----------------
__global__ void k_dinv(const u64* __restrict__ packed, float* __restrict__ dinv,
                       float* __restrict__ dinv2, const int* __restrict__ batch,
                       int* __restrict__ gs, int* __restrict__ ge, int n, int n2) {
    int i = blockIdx.x * 256 + threadIdx.x;
    if (i >= n2) return;
    u64 p = packed[i];
    float d = (float)(u32)p * 5.9604644775390625e-8f + 1.0f;   // 2^-24
    float r = rsqrtf(d);
    dinv[i] = r;
    dinv2[i] = r * r;
    if (i < n) {
        int b = batch[i];
        if (i == 0 || batch[i - 1] != b) atomicMin(&gs[b], i);
        if (i == n - 1 || batch[i + 1] != b) atomicMax(&ge[b], i + 1);
    }
}

// ---------------- exclusive scan of counts (hi words), st[n] = total ----------------
__global__ __launch_bounds__(1024) void k_scan(
    const u64* __restrict__ packed, int* __restrict__ st0, int* __restrict__ st1, int n)
{
    const u64* cnt = packed + (blockIdx.x ? n : 0);
    int* st = blockIdx.x ? st1 : st0;
    __shared__ int wsum[16];
    __shared__ int carry_s;
    int tid = threadIdx.x, lane = tid & 63, wid = tid >> 6;
    if (tid == 0) carry_s = 0;
    __syncthreads();
    for (int base = 0; base < n; base += 8192) {
        int i0 = base + tid * 8;
        int v[8];
        #pragma unroll
        for (int k = 0; k < 8; ++k) v[k] = (i0 + k < n) ? (int)(cnt[i0 + k] >> 32) : 0;
        int s[8]; int run = 0;
        #pragma unroll
        for (int k = 0; k < 8; ++k) { run += v[k]; s[k] = run; }
        int tsum = run, winc = tsum;
        #pragma unroll
        for (int d = 1; d < 64; d <<= 1) {
            int t = __shfl_up(winc, d);
            if (lane >= d) winc += t;
        }
        if (lane == 63) wsum[wid] = winc;
        __syncthreads();
        if (wid == 0) {
            int y = (lane < 16) ? wsum[lane] : 0;
            #pragma unroll
            for (int d = 1; d < 16; d <<= 1) {
                int t = __shfl_up(y, d);
                if (lane >= d) y += t;
            }
            if (lane < 16) wsum[lane] = y;
        }
        __syncthreads();
        int woff = (wid > 0) ? wsum[wid - 1] : 0;
        int tbase = carry_s + woff + winc - tsum;
        if (i0 < n) {
            int4 e0, e1;
            e0.x = tbase + s[0]-v[0]; e0.y = tbase + s[1]-v[1];
            e0.z = tbase + s[2]-v[2]; e0.w = tbase + s[3]-v[3];
            e1.x = tbase + s[4]-v[4]; e1.y = tbase + s[5]-v[5];
            e1.z = tbase + s[6]-v[6]; e1.w = tbase + s[7]-v[7];
            if (i0 + 8 <= n) {
                *(int4*)(st + i0) = e0;  *(int4*)(st + i0 + 4) = e1;
            } else {
                int vv[8] = {e0.x,e0.y,e0.z,e0.w,e1.x,e1.y,e1.z,e1.w};
                for (int k = 0; k < 8; ++k) if (i0 + k < n) st[i0 + k] = vv[k];
            }
        }
        __syncthreads();
        if (tid == 0) carry_s += wsum[15];
        __syncthreads();
    }
    if (tid == 0) st[n] = carry_s;
}

// ---------------- atomic-free scatter: slot = st[dst] + rank ----------------
__global__ void k_scatter(const int* __restrict__ ei, const float* __restrict__ ew,
                          const int* __restrict__ ein, const float* __restrict__ ewn,
                          const u32* __restrict__ rank_o, const u32* __restrict__ rank_n,
                          const float* __restrict__ dinv,
                          const int* __restrict__ st_o, const int* __restrict__ st_n,
                          u64* __restrict__ ev_o, u64* __restrict__ ev_n, int E, int n) {
    int e = blockIdx.x * 256 + threadIdx.x;
    if (e >= E) return;
    const int*   I = blockIdx.y ? ein : ei;
    const float* W = blockIdx.y ? ewn : ew;
    const u32*   R = blockIdx.y ? rank_n : rank_o;
    const int*   st = blockIdx.y ? st_n : st_o;
    const float* dv = dinv + (blockIdx.y ? n : 0);
    u64* ev = blockIdx.y ? ev_n : ev_o;
    int s = I[e], d = I[E + e];
    float v = dv[s] * W[e] * dv[d];
    int slot = st[d] + (int)R[e];
    ev[slot] = (u64)(u32)s | ((u64)__float_as_uint(v) << 32);
}

// ---------------- combined weights (both layers) + rinv tail ----------------
__global__ void k_combine(
    const float* __restrict__ W0o, const float* __restrict__ W0n, const float* __restrict__ W0f,
    const float* __restrict__ b0o, const float* __restrict__ b0n, const float* __restrict__ b0f,
    const float* __restrict__ W1o, const float* __restrict__ W1n, const float* __restrict__ W1f,
    const float* __restrict__ b1o, const float* __restrict__ b1n, const float* __restrict__ b1f,
    float* __restrict__ Wc0o, float* __restrict__ Wc0n, float* __restrict__ bc0,
    float* __restrict__ Wc1o, float* __restrict__ Wc1n, float* __restrict__ bc1,
    const int* __restrict__ gs, const int* __restrict__ ge, float* __restrict__ rinv)
{
    if (blockIdx.y == 0 && blockIdx.x == 0 && threadIdx.x < 64) {
        int c = ge[threadIdx.x] - gs[threadIdx.x];
        if (c < 1) c = 1;
        rinv[threadIdx.x] = 1.0f / (float)c;
    }
    const float* Wo = blockIdx.y ? W1o : W0o;
    const float* Wn = blockIdx.y ? W1n : W0n;
    const float* Wf = blockIdx.y ? W1f : W0f;
    const float* bo = blockIdx.y ? b1o : b0o;
    const float* bn = blockIdx.y ? b1n : b0n;
    const float* bf = blockIdx.y ? b1f : b0f;
    float* Wco = blockIdx.y ? Wc1o : Wc0o;
    float* Wcn = blockIdx.y ? Wc1n : Wc0n;
    float* bc  = blockIdx.y ? bc1  : bc0;
    int g = blockIdx.x * 256 + threadIdx.x;
    if (g >= DIM * DIM) return;
    int i = g / DIM, j = g % DIM;
    float so = 0.f, sn = 0.f;
    for (int k = 0; k < DIM; ++k) {
        so += Wo[i * DIM + k] * Wf[k * DIM + j];
        sn += Wn[i * DIM + k] * Wf[(DIM + k) * DIM + j];
    }
    Wco[g] = so;
    Wcn[g] = sn;
    if (i == 0) {
        float s = bf[j];
        for (int k = 0; k < DIM; ++k)
            s += bo[k] * Wf[k * DIM + j] + bn[k] * Wf[(DIM + k) * DIM + j];
        bc[j] = s;
    }
}

// ---------------- cast x (f32) -> packed bf16 ----------------
__global__ void k_cast(const float* __restrict__ x, u32* __restrict__ Xh, int total8) {
    int i = blockIdx.x * 256 + threadIdx.x;
    if (i >= total8) return;
    const float4* xv = (const float4*)x;
    float4 a = xv[i * 2], b = xv[i * 2 + 1];
    uint4 o;
    o.x = pk2(a.x, a.y); o.y = pk2(a.z, a.w);
    o.z = pk2(b.x, b.y); o.w = pk2(b.z, b.w);
    ((uint4*)Xh)[i] = o;
}

// ---------------- aggregation: bf16 gather, packed edges, 4-deep unroll ----------------
__global__ __launch_bounds__(256) void k_agg(
    const u32* __restrict__ Xh,
    const int* __restrict__ st_o, const u64* __restrict__ ev_o,
    const int* __restrict__ st_n, const u64* __restrict__ ev_n,
    const float* __restrict__ dinv2,
    float* __restrict__ outA, float* __restrict__ outB, int n)
{
    int wid = (blockIdx.x * 256 + threadIdx.x) >> 6;
    if (wid >= n) return;
    int lane = threadIdx.x & 63;
    int g = lane >> 4, sl = lane & 15;
    const int* st; const u64* ev; const float* d2p; float* out;
    if (blockIdx.y) { st = st_n; ev = ev_n; d2p = dinv2 + n; out = outB; }
    else            { st = st_o; ev = ev_o; d2p = dinv2;     out = outA; }

    float a0=0,a1=0,a2=0,a3=0,a4=0,a5=0;
    if (g == 0) {
        float d2 = d2p[wid];
        U3 xv = *(const U3*)(Xh + (size_t)wid * 48 + sl * 3);
        a0 = d2 * bl(xv.a); a1 = d2 * bh(xv.a);
        a2 = d2 * bl(xv.b); a3 = d2 * bh(xv.b);
        a4 = d2 * bl(xv.c); a5 = d2 * bh(xv.c);
    }
    int s = st[wid], e = st[wid + 1];
    int j = s + g;
    for (; j + 12 < e; j += 16) {
        u64 e0 = ev[j], e1 = ev[j + 4], e2 = ev[j + 8], e3 = ev[j + 12];
        int u0 = (int)(u32)e0, u1 = (int)(u32)e1, u2 = (int)(u32)e2, u3 = (int)(u32)e3;
        float w0 = __uint_as_float((u32)(e0 >> 32));
        float w1 = __uint_as_float((u32)(e1 >> 32));
        float w2 = __uint_as_float((u32)(e2 >> 32));
        float w3 = __uint_as_float((u32)(e3 >> 32));
        U3 x0 = *(const U3*)(Xh + (size_t)u0 * 48 + sl * 3);
        U3 x1 = *(const U3*)(Xh + (size_t)u1 * 48 + sl * 3);
        U3 x2 = *(const U3*)(Xh + (size_t)u2 * 48 + sl * 3);
        U3 x3 = *(const U3*)(Xh + (size_t)u3 * 48 + sl * 3);
        a0 += w0 * bl(x0.a); a1 += w0 * bh(x0.a);
        a2 += w0 * bl(x0.b); a3 += w0 * bh(x0.b);
        a4 += w0 * bl(x0.c); a5 += w0 * bh(x0.c);
        a0 += w1 * bl(x1.a); a1 += w1 * bh(x1.a);
        a2 += w1 * bl(x1.b); a3 += w1 * bh(x1.b);
        a4 += w1 * bl(x1.c); a5 += w1 * bh(x1.c);
        a0 += w2 * bl(x2.a); a1 += w2 * bh(x2.a);
        a2 += w2 * bl(x2.b); a3 += w2 * bh(x2.b);
        a4 += w2 * bl(x2.c); a5 += w2 * bh(x2.c);
        a0 += w3 * bl(x3.a); a1 += w3 * bh(x3.a);
        a2 += w3 * bl(x3.b); a3 += w3 * bh(x3.b);
        a4 += w3 * bl(x3.c); a5 += w3 * bh(x3.c);
    }
    for (; j < e; j += 4) {
        u64 ee = ev[j];
        int u = (int)(u32)ee;
        float w = __uint_as_float((u32)(ee >> 32));
        U3 xv = *(const U3*)(Xh + (size_t)u * 48 + sl * 3);
        a0 += w * bl(xv.a); a1 += w * bh(xv.a);
        a2 += w * bl(xv.b); a3 += w * bh(xv.b);
        a4 += w * bl(xv.c); a5 += w * bh(xv.c);
    }
    a0 += __shfl_xor(a0, 32); a1 += __shfl_xor(a1, 32); a2 += __shfl_xor(a2, 32);
    a3 += __shfl_xor(a3, 32); a4 += __shfl_xor(a4, 32); a5 += __shfl_xor(a5, 32);
    a0 += __shfl_xor(a0, 16); a1 += __shfl_xor(a1, 16); a2 += __shfl_xor(a2, 16);
    a3 += __shfl_xor(a3, 16); a4 += __shfl_xor(a4, 16); a5 += __shfl_xor(a5, 16);
    if (g == 0) {
        float2* O = (float2*)(out + (size_t)wid * DIM + sl * 6);
        float2 t;
        t.x = a0; t.y = a1; O[0] = t;
        t.x = a2; t.y = a3; O[1] = t;
        t.x = a4; t.y = a5; O[2] = t;
    }
}

// ---------------- H = relu(A@Wo + B@Wn + b); fused mean-pool; bf16 H write ----------------
#define RB 24
__global__ __launch_bounds__(192) void k_mmp(
    const float* __restrict__ A, const float* __restrict__ B,
    const float* __restrict__ Wo, const float* __restrict__ Wn,
    const float* __restrict__ bias, const int* __restrict__ batch,
    const float* __restrict__ rinv, float* __restrict__ outp,
    u32* __restrict__ Hh, int writeH, int n)
{
    __shared__ float lA[RB * 100];
    __shared__ float lB[RB * 100];
    __shared__ float lW[2][32 * DIM];
    __shared__ float pool[8 * DIM];
    int tid = threadIdx.x;
    int r0 = blockIdx.x * RB;
    int rows = min(RB, n - r0);
    int limit = rows * DIM;
    #pragma unroll
    for (int j = 0; j < 3; ++j) {
        int o = (tid + j * 192) * 4;
        float4 va = make_float4(0.f, 0.f, 0.f, 0.f), vb = va;
        if (o < limit) {
            va = *(const float4*)(A + (size_t)r0 * DIM + o);
            vb = *(const float4*)(B + (size_t)r0 * DIM + o);
        }
        int r = o / DIM, c = o % DIM;
        *(float4*)&lA[r * 100 + c] = va;
        *(float4*)&lB[r * 100 + c] = vb;
    }
    int cg = tid % 24, rg = tid / 24;
    float acc[3][4] = {};
    for (int kc = 0; kc < DIM; kc += 32) {
        __syncthreads();
        #pragma unroll
        for (int j = 0; j < 4; ++j) {
            int o = (tid + j * 192) * 4;
            *(float4*)&lW[0][o] = *(const float4*)(Wo + kc * DIM + o);
            *(float4*)&lW[1][o] = *(const float4*)(Wn + kc * DIM + o);
        }
        __syncthreads();
        for (int k = 0; k < 32; ++k) {
            float4 wo = *(const float4*)&lW[0][k * DIM + cg * 4];
            float4 wn = *(const float4*)&lW[1][k * DIM + cg * 4];
            int kk = kc + k;
            #pragma unroll
            for (int r = 0; r < 3; ++r) {
                float a = lA[(rg * 3 + r) * 100 + kk];
                float b = lB[(rg * 3 + r) * 100 + kk];
                acc[r][0] += a * wo.x + b * wn.x;
                acc[r][1] += a * wo.y + b * wn.y;
                acc[r][2] += a * wo.z + b * wn.z;
                acc[r][3] += a * wo.w + b * wn.w;
            }
        }
    }
    int cb = cg * 4;
    float4 bs = *(const float4*)(bias + cb);
    int g0 = batch[r0];
    int gL = batch[r0 + rows - 1];
    bool fast = (g0 == gL);
    float p0 = 0.f, p1 = 0.f, p2 = 0.f, p3 = 0.f;
    #pragma unroll
    for (int r = 0; r < 3; ++r) {
        int row = rg * 3 + r;
        if (row < rows) {
            float vx = fmaxf(acc[r][0] + bs.x, 0.f);
            float vy = fmaxf(acc[r][1] + bs.y, 0.f);
            float vz = fmaxf(acc[r][2] + bs.z, 0.f);
            float vw = fmaxf(acc[r][3] + bs.w, 0.f);
            int grow = r0 + row;
            if (writeH) {
                uint2 h; h.x = pk2(vx, vy); h.y = pk2(vz, vw);
                ((uint2*)Hh)[(size_t)grow * 24 + cg] = h;
            }
            if (fast) { p0 += vx; p1 += vy; p2 += vz; p3 += vw; }
            else {
                int gg = batch[grow];
                float rv = rinv[gg];
                atomicAdd(&outp[gg * DIM + cb + 0], vx * rv);
                atomicAdd(&outp[gg * DIM + cb + 1], vy * rv);
                atomicAdd(&outp[gg * DIM + cb + 2], vz * rv);
                atomicAdd(&outp[gg * DIM + cb + 3], vw * rv);
            }
        }
    }
    if (fast) {
        pool[rg * DIM + cb + 0] = p0;
        pool[rg * DIM + cb + 1] = p1;
        pool[rg * DIM + cb + 2] = p2;
        pool[rg * DIM + cb + 3] = p3;
        __syncthreads();
        if (tid < DIM) {
            float s2 = 0.f;
            #pragma unroll
            for (int r2 = 0; r2 < 8; ++r2) s2 += pool[r2 * DIM + tid];
            atomicAdd(&outp[g0 * DIM + tid], s2 * rinv[g0]);
        }
    }
}

extern "C" void kernel_launch(void* const* d_in, const int* in_sizes, int n_in,
                              void* d_out, int out_size, void* d_ws, size_t ws_size,
                              hipStream_t stream)
{
    const float* x     = (const float*)d_in[0];
    const int*   ei    = (const int*)d_in[1];
    const float* ew    = (const float*)d_in[2];
    const int*   batch = (const int*)d_in[3];
    const int*   ein   = (const int*)d_in[4];
    const float* ewn   = (const float*)d_in[5];
    const float* W0o = (const float*)d_in[7];
    const float* b0o = (const float*)d_in[8];
    const float* W0n = (const float*)d_in[9];
    const float* b0n = (const float*)d_in[10];
    const float* W0f = (const float*)d_in[11];
    const float* b0f = (const float*)d_in[12];
    const float* W1o = (const float*)d_in[13];
    const float* b1o = (const float*)d_in[14];
    const float* W1n = (const float*)d_in[15];
    const float* b1n = (const float*)d_in[16];
    const float* W1f = (const float*)d_in[17];
    const float* b1f = (const float*)d_in[18];

    const int N = in_sizes[0] / DIM;
    const int E = in_sizes[2];
    float* out = (float*)d_out;

    char* ws = (char*)d_ws;
    size_t off = 0;
    auto alloc = [&](size_t bytes) -> char* {
        char* p = ws + off;
        off += (bytes + 255) & ~(size_t)255;
        return p;
    };
    u64*   packed = (u64*)alloc((size_t)2 * N * 8);
    float* dinv   = (float*)alloc((size_t)2 * N * 4);
    float* dinv2  = (float*)alloc((size_t)2 * N * 4);
    u32*   rank_o = (u32*)alloc((size_t)E * 4);
    u32*   rank_n = (u32*)alloc((size_t)E * 4);
    int*   st_o   = (int*)alloc((size_t)(N + 1) * 4);
    int*   st_n   = (int*)alloc((size_t)(N + 1) * 4);
    u64*   ev_o   = (u64*)alloc((size_t)E * 8);
    u64*   ev_n   = (u64*)alloc((size_t)E * 8);
    u32*   Xh     = (u32*)alloc((size_t)N * 48 * 4);
    u32*   Hh     = (u32*)alloc((size_t)N * 48 * 4);
    float* fA     = (float*)alloc((size_t)N * DIM * 4);
    float* fB     = (float*)alloc((size_t)N * DIM * 4);
    float* Wc0o   = (float*)alloc(DIM * DIM * 4);
    float* Wc0n   = (float*)alloc(DIM * DIM * 4);
    float* Wc1o   = (float*)alloc(DIM * DIM * 4);
    float* Wc1n   = (float*)alloc(DIM * DIM * 4);
    float* bc0    = (float*)alloc(DIM * 4);
    float* bc1    = (float*)alloc(DIM * 4);
    float* rinv   = (float*)alloc(64 * 4);
    int*   gs     = (int*)alloc(64 * 4);
    int*   ge     = (int*)alloc(64 * 4);

    int eb = (E + 255) / 256;

    int initTot = 4 * N + out_size + 128;
    k_init<<<(initTot + 255) / 256, 256, 0, stream>>>((u32*)packed, out, gs, ge, 4 * N, out_size);
    k_deg<<<dim3(eb, 2), 256, 0, stream>>>(ei, ew, ein, ewn, packed, rank_o, rank_n, E, N);
    k_dinv<<<(2 * N + 255) / 256, 256, 0, stream>>>(packed, dinv, dinv2, batch, gs, ge, N, 2 * N);
    k_scan<<<2, 1024, 0, stream>>>(packed, st_o, st_n, N);
    k_scatter<<<dim3(eb, 2), 256, 0, stream>>>(ei, ew, ein, ewn, rank_o, rank_n, dinv,
                                               st_o, st_n, ev_o, ev_n, E, N);
    k_combine<<<dim3(36, 2), 256, 0, stream>>>(W0o, W0n, W0f, b0o, b0n, b0f,
                                               W1o, W1n, W1f, b1o, b1n, b1f,
                                               Wc0o, Wc0n, bc0, Wc1o, Wc1n, bc1,
                                               gs, ge, rinv);
    k_cast<<<(N * 12 + 255) / 256, 256, 0, stream>>>(x, Xh, N * 12);

    dim3 ag((N * 64 + 255) / 256, 2);
    int mb = (N + RB - 1) / RB;

    // layer 0
    k_agg<<<ag, 256, 0, stream>>>(Xh, st_o, ev_o, st_n, ev_n, dinv2, fA, fB, N);
    k_mmp<<<mb, 192, 0, stream>>>(fA, fB, Wc0o, Wc0n, bc0, batch, rinv, out, Hh, 1, N);
    // layer 1
    k_agg<<<ag, 256, 0, stream>>>(Hh, st_o, ev_o, st_n, ev_n, dinv2, fA, fB, N);
    k_mmp<<<mb, 192, 0, stream>>>(fA, fB, Wc1o, Wc1n, bc1, batch, rinv, out + 64 * DIM, Hh, 0, N);
}

// Round 5
// 305.739 us; speedup vs baseline: 2.7395x; 1.2449x over previous
//
#include <hip/hip_runtime.h>
#include <hip/hip_bf16.h>

#define DIM 96
typedef unsigned int u32;
typedef unsigned long long u64;
typedef __attribute__((ext_vector_type(8))) short short8;
typedef __attribute__((ext_vector_type(4))) float f32x4;

__device__ __forceinline__ u32 bfr(float f) {           // f32 -> bf16 bits (RNE)
    u32 b = __float_as_uint(f);
    return (b + 0x7fffu + ((b >> 16) & 1u)) >> 16;
}
__device__ __forceinline__ u32 pk2(float lo, float hi) { return bfr(lo) | (bfr(hi) << 16); }
__device__ __forceinline__ float bl(u32 u) { return __uint_as_float(u << 16); }
__device__ __forceinline__ float bh(u32 u) { return __uint_as_float(u & 0xffff0000u); }

struct __align__(4) U3 { u32 a, b, c; };

// ---------------- init: zero cnt[2N] + d_out, preset gs/ge ----------------
__global__ void k_init(u32* __restrict__ cnt, float* __restrict__ outp,
                       int* __restrict__ gs, int* __restrict__ ge, int n2, int osz) {
    int i = blockIdx.x * 256 + threadIdx.x;
    if (i < n2) cnt[i] = 0;
    int j = i - n2;
    if (j >= 0 && j < osz) outp[j] = 0.f;
    int k2 = j - osz;
    if (k2 >= 0 && k2 < 64) gs[k2] = 0x7fffffff;
    int k3 = k2 - 64;
    if (k3 >= 0 && k3 < 64) ge[k3] = 0;
}

// ---------------- count per dst (u32 atomic, rank = returned old); bounds tail ----------------
__global__ void k_deg(const int* __restrict__ ei, const int* __restrict__ ein,
                      u32* __restrict__ cnt, u32* __restrict__ rank_o, u32* __restrict__ rank_n,
                      const int* __restrict__ batch, int* __restrict__ gs, int* __restrict__ ge,
                      int E, int n) {
    int e = blockIdx.x * 256 + threadIdx.x;
    if (blockIdx.y == 0 && e < n) {
        int b = batch[e];
        if (e == 0 || batch[e - 1] != b) atomicMin(&gs[b], e);
        if (e == n - 1 || batch[e + 1] != b) atomicMax(&ge[b], e + 1);
    }
    if (e >= E) return;
    const int* I = blockIdx.y ? ein : ei;
    u32* cn = cnt + (blockIdx.y ? n : 0);
    u32* rk = blockIdx.y ? rank_n : rank_o;
    rk[e] = atomicAdd(&cn[I[E + e]], 1u);
}

// ---------------- exclusive scan of counts, 16 elems/thread, one block/set ----------------
__global__ __launch_bounds__(1024) void k_scan(
    const u32* __restrict__ cnt, int* __restrict__ st0, int* __restrict__ st1, int n)
{
    const u32* c = cnt + (blockIdx.x ? n : 0);
    int* st = blockIdx.x ? st1 : st0;
    __shared__ int wsum[16];
    __shared__ int carry_s;
    int tid = threadIdx.x, lane = tid & 63, wid = tid >> 6;
    if (tid == 0) carry_s = 0;
    __syncthreads();
    for (int base = 0; base < n; base += 16384) {
        int i0 = base + tid * 16;
        int v[16];
        if (i0 + 16 <= n) {
            #pragma unroll
            for (int q = 0; q < 4; ++q) {
                int4 t = *(const int4*)(c + i0 + q * 4);
                v[q*4] = t.x; v[q*4+1] = t.y; v[q*4+2] = t.z; v[q*4+3] = t.w;
            }
        } else {
            #pragma unroll
            for (int k = 0; k < 16; ++k) v[k] = (i0 + k < n) ? (int)c[i0 + k] : 0;
        }
        int ex[16]; int run = 0;
        #pragma unroll
        for (int k = 0; k < 16; ++k) { ex[k] = run; run += v[k]; }
        int tsum = run, winc = tsum;
        #pragma unroll
        for (int d = 1; d < 64; d <<= 1) {
            int t = __shfl_up(winc, d);
            if (lane >= d) winc += t;
        }
        if (lane == 63) wsum[wid] = winc;
        __syncthreads();
        if (wid == 0) {
            int y = (lane < 16) ? wsum[lane] : 0;
            #pragma unroll
            for (int d = 1; d < 16; d <<= 1) {
                int t = __shfl_up(y, d);
                if (lane >= d) y += t;
            }
            if (lane < 16) wsum[lane] = y;
        }
        __syncthreads();
        int woff = (wid > 0) ? wsum[wid - 1] : 0;
        int tbase = carry_s + woff + winc - tsum;
        if (i0 < n) {
            #pragma unroll
            for (int k = 0; k < 16; ++k) if (i0 + k < n) st[i0 + k] = tbase + ex[k];
        }
        __syncthreads();
        if (tid == 0) carry_s += wsum[15];
        __syncthreads();
    }
    if (tid == 0) st[n] = carry_s;
}

// ---------------- atomic-free scatter: ev[st[dst]+rank] = [w_f32 | src] ----------------
__global__ void k_scatter(const int* __restrict__ ei, const float* __restrict__ ew,
                          const int* __restrict__ ein, const float* __restrict__ ewn,
                          const u32* __restrict__ rank_o, const u32* __restrict__ rank_n,
                          const int* __restrict__ st_o, const int* __restrict__ st_n,
                          u64* __restrict__ ev_o, u64* __restrict__ ev_n, int E) {
    int e = blockIdx.x * 256 + threadIdx.x;
    if (e >= E) return;
    const int*   I = blockIdx.y ? ein : ei;
    const float* W = blockIdx.y ? ewn : ew;
    const u32*   R = blockIdx.y ? rank_n : rank_o;
    const int*   st = blockIdx.y ? st_n : st_o;
    u64* ev = blockIdx.y ? ev_n : ev_o;
    int s = I[e], d = I[E + e];
    int slot = st[d] + (int)R[e];
    ev[slot] = ((u64)__float_as_uint(W[e]) << 32) | (u32)s;
}

// ---------------- per-node weight sum -> dinv (both sets over 2N) ----------------
__global__ void k_wsum(const int* __restrict__ st_o, const u64* __restrict__ ev_o,
                       const int* __restrict__ st_n, const u64* __restrict__ ev_n,
                       float* __restrict__ dinv, int n) {
    int i = blockIdx.x * 256 + threadIdx.x;
    if (i >= 2 * n) return;
    const int* st; const u64* ev; int v;
    if (i < n) { st = st_o; ev = ev_o; v = i; }
    else       { st = st_n; ev = ev_n; v = i - n; }
    float s = 0.f;
    int a = st[v], b = st[v + 1];
    for (int j = a; j < b; ++j) s += __uint_as_float((u32)(ev[j] >> 32));
    dinv[i] = rsqrtf(s + 1.0f);
}

// ---------------- combined weights -> bf16 K-major Wt[96][192]; bias f32; rinv ----------------
__global__ void k_combine(
    const float* __restrict__ W0o, const float* __restrict__ W0n, const float* __restrict__ W0f,
    const float* __restrict__ b0o, const float* __restrict__ b0n, const float* __restrict__ b0f,
    const float* __restrict__ W1o, const float* __restrict__ W1n, const float* __restrict__ W1f,
    const float* __restrict__ b1o, const float* __restrict__ b1n, const float* __restrict__ b1f,
    unsigned short* __restrict__ Wt, float* __restrict__ bc,
    const int* __restrict__ gs, const int* __restrict__ ge, float* __restrict__ rinv)
{
    if (blockIdx.y == 0 && blockIdx.x == 0 && threadIdx.x < 64) {
        int c = ge[threadIdx.x] - gs[threadIdx.x];
        if (c < 1) c = 1;
        rinv[threadIdx.x] = 1.0f / (float)c;
    }
    int l = blockIdx.y;
    const float* Wo = l ? W1o : W0o;
    const float* Wn = l ? W1n : W0n;
    const float* Wf = l ? W1f : W0f;
    const float* bo = l ? b1o : b0o;
    const float* bn = l ? b1n : b0n;
    const float* bf = l ? b1f : b0f;
    unsigned short* wt = Wt + (size_t)l * 96 * 192;
    float* bcl = bc + l * DIM;
    int g = blockIdx.x * 256 + threadIdx.x;
    if (g >= DIM * DIM) return;
    int i = g / DIM, j = g % DIM;       // i = k-row (0..95), j = out col
    float so = 0.f, sn = 0.f;
    for (int k = 0; k < DIM; ++k) {
        so += Wo[i * DIM + k] * Wf[k * DIM + j];
        sn += Wn[i * DIM + k] * Wf[(DIM + k) * DIM + j];
    }
    wt[j * 192 + i]      = (unsigned short)bfr(so);
    wt[j * 192 + 96 + i] = (unsigned short)bfr(sn);
    if (i == 0) {
        float s = bf[j];
        for (int k = 0; k < DIM; ++k)
            s += bo[k] * Wf[k * DIM + j] + bn[k] * Wf[(DIM + k) * DIM + j];
        bcl[j] = s;
    }
}

// ---------------- cast x (f32) -> packed bf16 ----------------
__global__ void k_cast(const float* __restrict__ x, u32* __restrict__ Xh, int total8) {
    int i = blockIdx.x * 256 + threadIdx.x;
    if (i >= total8) return;
    const float4* xv = (const float4*)x;
    float4 a = xv[i * 2], b = xv[i * 2 + 1];
    uint4 o;
    o.x = pk2(a.x, a.y); o.y = pk2(a.z, a.w);
    o.z = pk2(b.x, b.y); o.w = pk2(b.z, b.w);
    ((uint4*)Xh)[i] = o;
}

// ---------------- aggregation: bf16 gather, norm folded in, bf16 out into fAB ----------------
__global__ __launch_bounds__(256) void k_agg(
    const u32* __restrict__ Xh,
    const int* __restrict__ st_o, const u64* __restrict__ ev_o,
    const int* __restrict__ st_n, const u64* __restrict__ ev_n,
    const float* __restrict__ dinv,
    u32* __restrict__ fAB, int n)
{
    int wid = (blockIdx.x * 256 + threadIdx.x) >> 6;
    if (wid >= n) return;
    int lane = threadIdx.x & 63;
    int g = lane >> 4, sl = lane & 15;
    const int* st; const u64* ev; const float* dv; int co;
    if (blockIdx.y) { st = st_n; ev = ev_n; dv = dinv + n; co = 48; }
    else            { st = st_o; ev = ev_o; dv = dinv;     co = 0; }

    float dr = dv[wid];
    float a0=0,a1=0,a2=0,a3=0,a4=0,a5=0;
    if (g == 0) {
        float d2 = dr * dr;
        U3 xv = *(const U3*)(Xh + (size_t)wid * 48 + sl * 3);
        a0 = d2 * bl(xv.a); a1 = d2 * bh(xv.a);
        a2 = d2 * bl(xv.b); a3 = d2 * bh(xv.b);
        a4 = d2 * bl(xv.c); a5 = d2 * bh(xv.c);
    }
    int s = st[wid], e = st[wid + 1];
    int j = s + g;
    for (; j + 12 < e; j += 16) {
        u64 e0 = ev[j], e1 = ev[j + 4], e2 = ev[j + 8], e3 = ev[j + 12];
        int u0 = (int)(u32)e0, u1 = (int)(u32)e1, u2 = (int)(u32)e2, u3 = (int)(u32)e3;
        float q0 = dv[u0], q1 = dv[u1], q2 = dv[u2], q3 = dv[u3];
        float w0 = __uint_as_float((u32)(e0 >> 32)) * dr * q0;
        float w1 = __uint_as_float((u32)(e1 >> 32)) * dr * q1;
        float w2 = __uint_as_float((u32)(e2 >> 32)) * dr * q2;
        float w3 = __uint_as_float((u32)(e3 >> 32)) * dr * q3;
        U3 x0 = *(const U3*)(Xh + (size_t)u0 * 48 + sl * 3);
        U3 x1 = *(const U3*)(Xh + (size_t)u1 * 48 + sl * 3);
        U3 x2 = *(const U3*)(Xh + (size_t)u2 * 48 + sl * 3);
        U3 x3 = *(const U3*)(Xh + (size_t)u3 * 48 + sl * 3);
        a0 += w0 * bl(x0.a); a1 += w0 * bh(x0.a);
        a2 += w0 * bl(x0.b); a3 += w0 * bh(x0.b);
        a4 += w0 * bl(x0.c); a5 += w0 * bh(x0.c);
        a0 += w1 * bl(x1.a); a1 += w1 * bh(x1.a);
        a2 += w1 * bl(x1.b); a3 += w1 * bh(x1.b);
        a4 += w1 * bl(x1.c); a5 += w1 * bh(x1.c);
        a0 += w2 * bl(x2.a); a1 += w2 * bh(x2.a);
        a2 += w2 * bl(x2.b); a3 += w2 * bh(x2.b);
        a4 += w2 * bl(x2.c); a5 += w2 * bh(x2.c);
        a0 += w3 * bl(x3.a); a1 += w3 * bh(x3.a);
        a2 += w3 * bl(x3.b); a3 += w3 * bh(x3.b);
        a4 += w3 * bl(x3.c); a5 += w3 * bh(x3.c);
    }
    for (; j < e; j += 4) {
        u64 ee = ev[j];
        int u = (int)(u32)ee;
        float w = __uint_as_float((u32)(ee >> 32)) * dr * dv[u];
        U3 xv = *(const U3*)(Xh + (size_t)u * 48 + sl * 3);
        a0 += w * bl(xv.a); a1 += w * bh(xv.a);
        a2 += w * bl(xv.b); a3 += w * bh(xv.b);
        a4 += w * bl(xv.c); a5 += w * bh(xv.c);
    }
    a0 += __shfl_xor(a0, 32); a1 += __shfl_xor(a1, 32); a2 += __shfl_xor(a2, 32);
    a3 += __shfl_xor(a3, 32); a4 += __shfl_xor(a4, 32); a5 += __shfl_xor(a5, 32);
    a0 += __shfl_xor(a0, 16); a1 += __shfl_xor(a1, 16); a2 += __shfl_xor(a2, 16);
    a3 += __shfl_xor(a3, 16); a4 += __shfl_xor(a4, 16); a5 += __shfl_xor(a5, 16);
    if (g == 0) {
        U3 o;
        o.a = pk2(a0, a1); o.b = pk2(a2, a3); o.c = pk2(a4, a5);
        *(U3*)(fAB + (size_t)wid * 96 + co + sl * 3) = o;
    }
}

// ---------------- MFMA GEMM: relu(fAB[N][192]bf16 @ Wt + bias); pool; bf16 H ----------------
__global__ __launch_bounds__(256) void k_mmp(
    const u32* __restrict__ fAB, const unsigned short* __restrict__ Wtg,
    const float* __restrict__ bias, const int* __restrict__ batch,
    const int* __restrict__ gs, const int* __restrict__ ge,
    const float* __restrict__ rinv, float* __restrict__ outp,
    u32* __restrict__ Hh, int writeH, int n)
{
    __shared__ unsigned short sW[96 * 200];       // Wt: [col][k], padded stride 200
    __shared__ float tile[64][100];
    int tid = threadIdx.x;
    for (int m = tid; m < 2304; m += 256) {       // 96*192/8 short8 chunks
        int j = m / 24, k = (m % 24) * 8;
        *(uint4*)&sW[j * 200 + k] = *(const uint4*)&Wtg[j * 192 + k];
    }
    __syncthreads();
    int r0 = blockIdx.x * 64;
    int rows = min(64, n - r0);
    int lane = tid & 63, wv = tid >> 6;
    int rl = lane & 15;
    int kg = lane >> 4;
    int rowg = r0 + wv * 16 + rl;
    int rc = min(rowg, n - 1);
    const short8* Arow = (const short8*)(fAB + (size_t)rc * 96);
    f32x4 acc[6];
    #pragma unroll
    for (int c = 0; c < 6; ++c) acc[c] = (f32x4){0.f, 0.f, 0.f, 0.f};
    #pragma unroll
    for (int t = 0; t < 6; ++t) {
        short8 a = Arow[t * 4 + kg];
        #pragma unroll
        for (int c = 0; c < 6; ++c) {
            short8 b = *(const short8*)&sW[(c * 16 + rl) * 200 + t * 32 + kg * 8];
            acc[c] = __builtin_amdgcn_mfma_f32_16x16x32_bf16(a, b, acc[c], 0, 0, 0);
        }
    }
    #pragma unroll
    for (int c = 0; c < 6; ++c) {
        int col = c * 16 + rl;
        float bs = bias[col];
        #pragma unroll
        for (int q = 0; q < 4; ++q) {
            int lr = wv * 16 + kg * 4 + q;
            tile[lr][col] = fmaxf(acc[c][q] + bs, 0.f);
        }
    }
    __syncthreads();
    if (writeH) {
        for (int m = tid; m < rows * 48; m += 256) {
            int row = m / 48, cp = m % 48;
            Hh[(size_t)(r0 + row) * 48 + cp] = pk2(tile[row][cp * 2], tile[row][cp * 2 + 1]);
        }
    }
    if (tid < DIM) {
        int gfirst = batch[r0], glast = batch[r0 + rows - 1];
        for (int g = gfirst; g <= glast; ++g) {
            int lo = max(gs[g] - r0, 0), hi = min(ge[g] - r0, rows);
            if (lo < hi) {
                float s = 0.f;
                for (int r = lo; r < hi; ++r) s += tile[r][tid];
                atomicAdd(&outp[g * DIM + tid], s * rinv[g]);
            }
        }
    }
}

extern "C" void kernel_launch(void* const* d_in, const int* in_sizes, int n_in,
                              void* d_out, int out_size, void* d_ws, size_t ws_size,
                              hipStream_t stream)
{
    const float* x     = (const float*)d_in[0];
    const int*   ei    = (const int*)d_in[1];
    const float* ew    = (const float*)d_in[2];
    const int*   batch = (const int*)d_in[3];
    const int*   ein   = (const int*)d_in[4];
    const float* ewn   = (const float*)d_in[5];
    const float* W0o = (const float*)d_in[7];
    const float* b0o = (const float*)d_in[8];
    const float* W0n = (const float*)d_in[9];
    const float* b0n = (const float*)d_in[10];
    const float* W0f = (const float*)d_in[11];
    const float* b0f = (const float*)d_in[12];
    const float* W1o = (const float*)d_in[13];
    const float* b1o = (const float*)d_in[14];
    const float* W1n = (const float*)d_in[15];
    const float* b1n = (const float*)d_in[16];
    const float* W1f = (const float*)d_in[17];
    const float* b1f = (const float*)d_in[18];

    const int N = in_sizes[0] / DIM;
    const int E = in_sizes[2];
    float* out = (float*)d_out;

    char* ws = (char*)d_ws;
    size_t off = 0;
    auto alloc = [&](size_t bytes) -> char* {
        char* p = ws + off;
        off += (bytes + 255) & ~(size_t)255;
        return p;
    };
    u32*   cnt    = (u32*)alloc((size_t)2 * N * 4);
    u32*   rank_o = (u32*)alloc((size_t)E * 4);
    u32*   rank_n = (u32*)alloc((size_t)E * 4);
    int*   st_o   = (int*)alloc((size_t)(N + 1) * 4);
    int*   st_n   = (int*)alloc((size_t)(N + 1) * 4);
    u64*   ev_o   = (u64*)alloc((size_t)E * 8);
    u64*   ev_n   = (u64*)alloc((size_t)E * 8);
    float* dinv   = (float*)alloc((size_t)2 * N * 4);
    u32*   Xh     = (u32*)alloc((size_t)N * 48 * 4);
    u32*   Hh     = (u32*)alloc((size_t)N * 48 * 4);
    u32*   fAB    = (u32*)alloc((size_t)N * 96 * 4);
    unsigned short* Wt = (unsigned short*)alloc((size_t)2 * 96 * 192 * 2);
    float* bc     = (float*)alloc(2 * DIM * 4);
    float* rinv   = (float*)alloc(64 * 4);
    int*   gs     = (int*)alloc(64 * 4);
    int*   ge     = (int*)alloc(64 * 4);

    int eb = (E + 255) / 256;

    int initTot = 2 * N + out_size + 128;
    k_init<<<(initTot + 255) / 256, 256, 0, stream>>>(cnt, out, gs, ge, 2 * N, out_size);
    k_deg<<<dim3(eb, 2), 256, 0, stream>>>(ei, ein, cnt, rank_o, rank_n, batch, gs, ge, E, N);
    k_scan<<<2, 1024, 0, stream>>>(cnt, st_o, st_n, N);
    k_scatter<<<dim3(eb, 2), 256, 0, stream>>>(ei, ew, ein, ewn, rank_o, rank_n,
                                               st_o, st_n, ev_o, ev_n, E);
    k_wsum<<<(2 * N + 255) / 256, 256, 0, stream>>>(st_o, ev_o, st_n, ev_n, dinv, N);
    k_combine<<<dim3(36, 2), 256, 0, stream>>>(W0o, W0n, W0f, b0o, b0n, b0f,
                                               W1o, W1n, W1f, b1o, b1n, b1f,
                                               Wt, bc, gs, ge, rinv);
    k_cast<<<(N * 12 + 255) / 256, 256, 0, stream>>>(x, Xh, N * 12);

    dim3 ag(((size_t)N * 64 + 255) / 256, 2);
    int mb = (N + 63) / 64;

    // layer 0
    k_agg<<<ag, 256, 0, stream>>>(Xh, st_o, ev_o, st_n, ev_n, dinv, fAB, N);
    k_mmp<<<mb, 256, 0, stream>>>(fAB, Wt, bc, batch, gs, ge, rinv, out, Hh, 1, N);
    // layer 1
    k_agg<<<ag, 256, 0, stream>>>(Hh, st_o, ev_o, st_n, ev_n, dinv, fAB, N);
    k_mmp<<<mb, 256, 0, stream>>>(fAB, Wt + (size_t)96 * 192, bc + DIM, batch, gs, ge, rinv,
                                  out + 64 * DIM, Hh, 0, N);
}